// Round 12
// baseline (317.332 us; speedup 1.0000x reference)
//
#include <hip/hip_runtime.h>

namespace {
constexpr int NB = 4;      // batch
constexpr int CI = 128;    // input channels
constexpr int NP = 1024;   // points
constexpr int MM = 4096;   // N*UP
constexpr float EPSBN = 1e-5f;
constexpr float LOG2E = 1.4426950408889634f;

constexpr size_t OPS_SH = 2162688;       // Opart split stride in SHORTS (B*MM*132)
// workspace offsets (floats)
constexpr size_t OFF_OP   = 0;           // 6 bf16 splits = 6488064 floats (overlaid: DIST / Pm,Qm / Hraw,FGraw / Y1)
constexpr size_t OFF_DIST = 0;           // 4194304
constexpr size_t OFF_PM   = 0;           // 2097152
constexpr size_t OFF_QM   = 2097152;     // 2097152
constexpr size_t OFF_HRAW = 0;           // 2359296 (B,144,MM) f32
constexpr size_t OFF_FGRAW= 2359296;     // 1048576 (B,MM,64) f32  -> ends 3407872
constexpr size_t OFF_Y1   = 0;           // (B,MM,256) bf16 = 2097152 floats
constexpr size_t OFF_FGT  = 6488064;     // (B,MM,64) bf16 = 524288 floats
constexpr size_t OFF_HB   = 7012352;     // (B,144,MM) bf16 = 1179648 floats
constexpr size_t OFF_A16  = 6488064;     // (B,MM,160) bf16 = 1310720 floats (over FGT/HB after omfma)
constexpr size_t OFF_X16  = 8192000;     // (B,MM,160) bf16 = 1310720 floats
constexpr size_t OFF_LSE  = 9502720;     // 16384
constexpr size_t OFF_LSEP = 9519104;     // 131072
constexpr size_t OFF_STATS= 9650176;     // 65536
constexpr size_t OFF_ABE  = 9715712;     // 1024
constexpr size_t OFF_ABFG = 9716736;     // 128
constexpr size_t OFF_ABH  = 9716864;     // 512
constexpr size_t OFF_FGP  = 9717376;     // 8192
constexpr size_t OFF_BIAS = 9725568;     // 640
constexpr size_t OFF_W16  = 9726208;     // 53504 (107008 shorts)
constexpr size_t OFF_KNN  = 9779712;     // 73728 ints
constexpr size_t OFF_XN   = 9853440;     // (B,128,1024) f32 = 524288 (normalized, ch-major, for fp32 dist)
constexpr size_t OFF_SQ   = 10377728;    // 4096
constexpr size_t OFF_XR   = 10381824;    // (B,1024,128) bf16 raw = 262144 floats
constexpr size_t OFF_WPQ  = 10643968;    // 65536 floats (131072 shorts) -> ends 10709504
// W16 sub-offsets (shorts)
constexpr size_t W16_FG = 0;       // 64x160
constexpr size_t W16_H  = 10240;   // 144x160
constexpr size_t W16_C1 = 33280;   // 256x160
constexpr size_t W16_C2 = 74240;   // 128x256
// BIAS sub-offsets (floats)
constexpr size_t B_FG = 0, B_H = 64, B_C1 = 208, B_C2 = 464;
} // namespace

typedef __attribute__((ext_vector_type(8))) short short8;
typedef __attribute__((ext_vector_type(4))) float f32x4;
#define MFMA16(A, B, C) __builtin_amdgcn_mfma_f32_16x16x32_bf16(A, B, C, 0, 0, 0)

__device__ inline unsigned short f2bf(float x) {
  unsigned int u = __float_as_uint(x);
  unsigned int r = u + 0x7fff + ((u >> 16) & 1);
  return (unsigned short)(r >> 16);
}
__device__ inline float bf2f(unsigned short s) {
  return __uint_as_float(((unsigned int)s) << 16);
}
__device__ inline unsigned cvtpk(float lo, float hi) {
  unsigned r;
  asm("v_cvt_pk_bf16_f32 %0, %1, %2" : "=v"(r) : "v"(lo), "v"(hi));
  return r;
}

// ---------------- prep: conv weights/biases + edge Wp/Wq -> bf16 ----------------
__global__ __launch_bounds__(256) void k_prep(const float* __restrict__ Wf, const float* __restrict__ Wg,
                                              const float* __restrict__ Wh, const float* __restrict__ W1,
                                              const float* __restrict__ W2, const float* __restrict__ bf,
                                              const float* __restrict__ bg, const float* __restrict__ bh,
                                              const float* __restrict__ b1, const float* __restrict__ b2,
                                              const float* __restrict__ Wa, const float* __restrict__ Wb,
                                              unsigned short* __restrict__ W16, float* __restrict__ BIAS,
                                              unsigned short* __restrict__ WPQ) {
  int i = blockIdx.x * 256 + threadIdx.x;
  if (i < 107008) {
    float v = 0.f;
    if (i < 10240) { int o = i / 160, c = i % 160; if (c < 130) v = (o < 32) ? Wf[o * 130 + c] : Wg[(o - 32) * 130 + c]; }
    else if (i < 33280) { int r = i - 10240; int o = r / 160, c = r % 160; if (o < 130 && c < 130) v = Wh[o * 130 + c]; }
    else if (i < 74240) { int r = i - 33280; int o = r / 160, c = r % 160; if (c < 130) v = W1[o * 130 + c]; }
    else { int r = i - 74240; int o = r / 256, c = r % 256; v = W2[o * 256 + c]; }
    W16[i] = f2bf(v);
  } else if (i < 107648) {
    int j = i - 107008; float v = 0.f;
    if (j < 64) v = (j < 32) ? bf[j] : bg[j - 32];
    else if (j < 208) { int c = j - 64; if (c < 130) v = bh[c]; }
    else if (j < 464) v = b1[j - 208];
    else if (j < 592) v = b2[j - 464];
    BIAS[j] = v;
  } else if (i < 238720) {
    int j = i - 107648;
    int e = j >> 16;
    int rem = j & 65535;
    int pq = rem >> 15;
    int rr = rem & 32767;
    int o = rr >> 7, c = rr & 127;
    const float* W = e ? Wb : Wa;
    float w1 = W[o * 256 + c], w2 = W[o * 256 + 128 + c];
    float v = pq ? w2 : (w1 - w2);
    WPQ[j] = f2bf(v);
  }
}

// ---------------- K1: normalize -> fp32 XN ch-major (for dist), raw bf16 n-major, sq ----------------
__global__ __launch_bounds__(256) void k_norm(const float* __restrict__ x,
                                              float* __restrict__ xn,
                                              unsigned short* __restrict__ XR,
                                              float* __restrict__ sq) {
  int t = blockIdx.x * 256 + threadIdx.x;   // b*1024+n
  int b = t >> 10, n = t & 1023;
  const float* xb = x + (size_t)b * CI * NP + n;
  float ss = 0.f;
  #pragma unroll 4
  for (int c = 0; c < CI; ++c) { float v = xb[(size_t)c * NP]; ss += v * v; }
  float inv = 1.f / fmaxf(sqrtf(ss), 1e-12f);
  float* xo = xn + (size_t)b * CI * NP + n;
  float s2 = 0.f;
  for (int c0 = 0; c0 < 128; c0 += 8) {
    unsigned rw[4];
    #pragma unroll
    for (int j = 0; j < 4; ++j) {
      float va = xb[(size_t)(c0 + 2 * j) * NP];
      float vb = xb[(size_t)(c0 + 2 * j + 1) * NP];
      float na = va * inv, nb = vb * inv;
      s2 += na * na + nb * nb;
      xo[(size_t)(c0 + 2 * j) * NP] = na;
      xo[(size_t)(c0 + 2 * j + 1) * NP] = nb;
      rw[j] = (unsigned)f2bf(va) | ((unsigned)f2bf(vb) << 16);
    }
    uint4 r4 = {rw[0], rw[1], rw[2], rw[3]};
    *(uint4*)&XR[(size_t)t * 128 + c0] = r4;
  }
  sq[t] = s2;
}

// ---------------- K2: pairwise distance, fp32 128x128 tile (exact kNN path; same fp order) ----------------
// grid (8 mtiles, 8 ntiles, 4 b), 256 thr; each thread 8x8 outputs
__global__ __launch_bounds__(256) void k_dist(const float* __restrict__ xn,
                                              const float* __restrict__ sq,
                                              float* __restrict__ dist) {
  __shared__ float As[32][132], Bs[32][132];
  int t = threadIdx.x;
  int m0 = blockIdx.x * 128, n0 = blockIdx.y * 128, b = blockIdx.z;
  int mg = t & 15, ng = t >> 4;
  float acc[8][8];
  #pragma unroll
  for (int i = 0; i < 8; ++i)
    #pragma unroll
    for (int j = 0; j < 8; ++j) acc[i][j] = 0.f;
  for (int cc = 0; cc < 128; cc += 32) {
    __syncthreads();
    for (int idx = t; idx < 4096; idx += 256) {
      int c = idx >> 7, j = idx & 127;
      As[c][j] = xn[((size_t)b * CI + cc + c) * NP + n0 + j];
      Bs[c][j] = xn[((size_t)b * CI + cc + c) * NP + m0 + j];
    }
    __syncthreads();
    #pragma unroll
    for (int c = 0; c < 32; ++c) {
      float4 a0 = *(const float4*)&As[c][ng * 8];
      float4 a1 = *(const float4*)&As[c][ng * 8 + 4];
      float4 b0 = *(const float4*)&Bs[c][mg * 8];
      float4 b1 = *(const float4*)&Bs[c][mg * 8 + 4];
      float av[8] = {a0.x, a0.y, a0.z, a0.w, a1.x, a1.y, a1.z, a1.w};
      float bv[8] = {b0.x, b0.y, b0.z, b0.w, b1.x, b1.y, b1.z, b1.w};
      #pragma unroll
      for (int i = 0; i < 8; ++i)
        #pragma unroll
        for (int j = 0; j < 8; ++j) acc[i][j] += av[i] * bv[j];
    }
  }
  #pragma unroll
  for (int i = 0; i < 8; ++i) {
    int n = n0 + ng * 8 + i;
    float sn = sq[b * NP + n];
    #pragma unroll
    for (int jq = 0; jq < 2; ++jq) {
      float4 r;
      int mb = m0 + mg * 8 + jq * 4;
      r.x = sn + sq[b * NP + mb + 0] - 2.f * acc[i][jq * 4 + 0];
      r.y = sn + sq[b * NP + mb + 1] - 2.f * acc[i][jq * 4 + 1];
      r.z = sn + sq[b * NP + mb + 2] - 2.f * acc[i][jq * 4 + 2];
      r.w = sn + sq[b * NP + mb + 3] - 2.f * acc[i][jq * 4 + 3];
      *(float4*)&dist[((size_t)b * NP + n) * NP + mb] = r;
    }
  }
}

// ---------------- K3: top-18 nearest per row ----------------
__global__ __launch_bounds__(64) void k_knn(const float* __restrict__ dist,
                                            int* __restrict__ knn) {
  int row = blockIdx.x;
  int l = threadIdx.x;
  const float* dr = dist + (size_t)row * NP;
  float d[16];
  #pragma unroll
  for (int i = 0; i < 16; ++i) d[i] = dr[l + 64 * i];
  for (int s = 0; s < 18; ++s) {
    float best = __builtin_inff(); int bslot = -1;
    #pragma unroll
    for (int i = 0; i < 16; ++i) if (d[i] < best) { best = d[i]; bslot = i; }
    int bidx = (bslot >= 0) ? (l + 64 * bslot) : 0x7fffffff;
    float bd = best; int bi = bidx;
    #pragma unroll
    for (int off = 32; off > 0; off >>= 1) {
      float od = __shfl_xor(bd, off);
      int   oi = __shfl_xor(bi, off);
      if (od < bd || (od == bd && oi < bi)) { bd = od; bi = oi; }
    }
    if (l == 0) knn[row * 18 + s] = bi;
    if ((bi & 63) == l) d[bi >> 6] = __builtin_inff();
  }
}

// ---------------- K4: P/Q pre-GEMMs via MFMA, m-major f32 out ----------------
__global__ __launch_bounds__(256) void k_pqm(const unsigned short* __restrict__ XR,
                                             const unsigned short* __restrict__ WPQ,
                                             float* __restrict__ Pm,
                                             float* __restrict__ Qm) {
  int t = threadIdx.x; int w = t >> 6; int l = t & 63;
  int lm = l & 15, g = l >> 4;
  int nt = blockIdx.x, oq = blockIdx.y, z = blockIdx.z;
  int e = z >> 2, b = z & 3;
  int srow = nt * 64 + w * 16 + lm;
  const unsigned short* sp = XR + ((size_t)b * 1024 + srow) * 128 + 8 * g;
  const unsigned short* wpp = WPQ + ((size_t)(e * 2 + 0) * 256 + oq * 64 + lm) * 128 + 8 * g;
  const unsigned short* wqq = WPQ + ((size_t)(e * 2 + 1) * 256 + oq * 64 + lm) * 128 + 8 * g;
  f32x4 accp[4], accq[4];
  #pragma unroll
  for (int i = 0; i < 4; ++i) { accp[i] = {0.f, 0.f, 0.f, 0.f}; accq[i] = {0.f, 0.f, 0.f, 0.f}; }
  #pragma unroll
  for (int cc = 0; cc < 4; ++cc) {
    short8 bfr = *(const short8*)(sp + cc * 32);
    #pragma unroll
    for (int ct = 0; ct < 4; ++ct) {
      short8 ap = *(const short8*)(wpp + (size_t)ct * 16 * 128 + cc * 32);
      accp[ct] = MFMA16(ap, bfr, accp[ct]);
      short8 aq = *(const short8*)(wqq + (size_t)ct * 16 * 128 + cc * 32);
      accq[ct] = MFMA16(aq, bfr, accq[ct]);
    }
  }
  int eb = e * 4 + b;
  #pragma unroll
  for (int ct = 0; ct < 4; ++ct) {
    int o0 = oq * 64 + ct * 16 + 4 * g;
    float4 rp = {accp[ct][0], accp[ct][1], accp[ct][2], accp[ct][3]};
    float4 rq = {accq[ct][0], accq[ct][1], accq[ct][2], accq[ct][3]};
    *(float4*)&Pm[((size_t)eb * 1024 + srow) * 256 + o0] = rp;
    *(float4*)&Qm[((size_t)eb * 1024 + srow) * 256 + o0] = rq;
  }
}

// ---------------- K5: edge BN stats partials ----------------
__global__ __launch_bounds__(256) void k_edge_stats(const float* __restrict__ Pm,
                                                    const float* __restrict__ Qm,
                                                    const int* __restrict__ knn,
                                                    float* __restrict__ stats) {
  int o = threadIdx.x;
  int chunk = blockIdx.x, b = blockIdx.y, e = blockIdx.z;
  int eb = e * 4 + b;
  float s = 0.f, s2 = 0.f;
  for (int nn = 0; nn < 64; ++nn) {
    int n = chunk * 64 + nn;
    float p = Pm[((size_t)eb * 1024 + n) * 256 + o];
    const int* kn = knn + (b * 1024 + n) * 18;
    #pragma unroll
    for (int kk = 0; kk < 9; ++kk) {
      int j = kn[e ? 2 * kk : kk];
      float v = p + Qm[((size_t)eb * 1024 + j) * 256 + o];
      s += v; s2 += v * v;
    }
  }
  size_t idx = ((((size_t)e * 4 + b) * 16 + chunk) * 256 + o) * 2;
  stats[idx] = s; stats[idx + 1] = s2;
}

// ---------------- K6: finalize edge BN ----------------
__global__ __launch_bounds__(256) void k_edge_fin(const float* __restrict__ stats,
                                                  const float* __restrict__ gna, const float* __restrict__ bta,
                                                  const float* __restrict__ gnb, const float* __restrict__ btb,
                                                  float* __restrict__ ab) {
  int i = blockIdx.x * 256 + threadIdx.x;
  if (i >= 512) return;
  int e = i >> 8, o = i & 255;
  float s = 0.f, s2 = 0.f;
  for (int b = 0; b < 4; ++b)
    for (int ch = 0; ch < 16; ++ch) {
      size_t idx = ((((size_t)e * 4 + b) * 16 + ch) * 256 + o) * 2;
      s += stats[idx]; s2 += stats[idx + 1];
    }
  float cnt = 4.0f * 1024.0f * 9.0f;
  float mean = s / cnt;
  float var = s2 / cnt - mean * mean;
  float g = e ? gnb[o] : gna[o];
  float bt = e ? btb[o] : bta[o];
  float alpha = g * rsqrtf(var + EPSBN);
  ab[i * 2] = alpha; ab[i * 2 + 1] = bt - mean * alpha;
}

// ---------------- K7: edge apply + max-over-k -> X16 (B,MM,160) bf16 ----------------
__global__ __launch_bounds__(256) void k_edge_apply(const float* __restrict__ Pm,
                                                    const float* __restrict__ Qm,
                                                    const int* __restrict__ knn,
                                                    const float* __restrict__ ab,
                                                    unsigned short* __restrict__ X16) {
  __shared__ int knl[18];
  int t = threadIdx.x;
  int n = blockIdx.x, b = blockIdx.y;
  if (t < 18) knl[t] = knn[(b * 1024 + n) * 18 + t];
  __syncthreads();
  int e = t >> 7, oo = t & 127;
  int eb = e * 4 + b;
  const float* Pr = Pm + ((size_t)eb * 1024 + n) * 256;
  const float* Qb = Qm + (size_t)eb * 1024 * 256;
  float p0 = Pr[oo], p1 = Pr[oo + 128];
  float a0 = ab[(e * 256 + oo) * 2], be0 = ab[(e * 256 + oo) * 2 + 1];
  float a1 = ab[(e * 256 + oo + 128) * 2], be1 = ab[(e * 256 + oo + 128) * 2 + 1];
  float mx0 = -__builtin_inff(), mx1 = -__builtin_inff();
  #pragma unroll
  for (int kk = 0; kk < 9; ++kk) {
    int j = knl[e ? 2 * kk : kk];
    const float* Qr = Qb + (size_t)j * 256;
    mx0 = fmaxf(mx0, fmaf(a0, p0 + Qr[oo], be0));
    mx1 = fmaxf(mx1, fmaf(a1, p1 + Qr[oo + 128], be1));
  }
  int u0 = e << 1, u1 = (e << 1) | 1;
  X16[((size_t)b * MM + 4 * n + u0) * 160 + oo] = f2bf(fmaxf(mx0, 0.f));
  X16[((size_t)b * MM + 4 * n + u1) * 160 + oo] = f2bf(fmaxf(mx1, 0.f));
  if (t < 128) {
    int u = t >> 5, c = 128 + (t & 31);
    int gr = n >> 8;
    float v = (c == 128) ? ((gr < 2) ? -0.2f : 0.2f) : (c == 129) ? ((gr & 1) ? 0.2f : -0.2f) : 0.f;
    X16[((size_t)b * MM + 4 * n + u) * 160 + c] = f2bf(v);
  }
}

// ---------------- MFMA 1x1 conv ----------------
// OUTMODE 0: f32 m-major | 1: bf16 m-major | 2: f32 ch-major
template <int KSTEPS, int CTPER, int OUTMODE, bool RELU>
__global__ __launch_bounds__(256) void k_convm(const unsigned short* __restrict__ src,
                                               const unsigned short* __restrict__ W16,
                                               const float* __restrict__ bias,
                                               float* __restrict__ dstF,
                                               unsigned short* __restrict__ dstB,
                                               int outld, int rows) {
  constexpr int LD = KSTEPS * 32;
  int t = threadIdx.x; int w = t >> 6; int l = t & 63;
  int lm = l & 15, g = l >> 4;
  int b = blockIdx.z; int ct0 = blockIdx.y * CTPER;
  int srow = blockIdx.x * 64 + w * 16 + lm;
  const unsigned short* sp = src + ((size_t)b * MM + srow) * LD + 8 * g;
  const unsigned short* wp = W16 + ((size_t)ct0 * 16 + lm) * LD + 8 * g;
  f32x4 acc[CTPER];
  #pragma unroll
  for (int i = 0; i < CTPER; ++i) acc[i] = {0.f, 0.f, 0.f, 0.f};
  #pragma unroll
  for (int cc = 0; cc < KSTEPS; ++cc) {
    short8 bfr = *(const short8*)(sp + cc * 32);
    #pragma unroll
    for (int ct = 0; ct < CTPER; ++ct) {
      short8 af = *(const short8*)(wp + (size_t)ct * 16 * LD + cc * 32);
      acc[ct] = MFMA16(af, bfr, acc[ct]);
    }
  }
  #pragma unroll
  for (int ct = 0; ct < CTPER; ++ct) {
    int o0 = (ct0 + ct) * 16 + 4 * g;
    float4 bv = *(const float4*)&bias[o0];
    float v[4] = {acc[ct][0] + bv.x, acc[ct][1] + bv.y, acc[ct][2] + bv.z, acc[ct][3] + bv.w};
    if (RELU) { v[0] = fmaxf(v[0], 0.f); v[1] = fmaxf(v[1], 0.f); v[2] = fmaxf(v[2], 0.f); v[3] = fmaxf(v[3], 0.f); }
    if (OUTMODE == 0) {
      float4 r = {v[0], v[1], v[2], v[3]};
      *(float4*)&dstF[((size_t)b * MM + srow) * outld + o0] = r;
    } else if (OUTMODE == 1) {
      uint2 pk;
      pk.x = cvtpk(v[0], v[1]);
      pk.y = cvtpk(v[2], v[3]);
      *(uint2*)&dstB[((size_t)b * MM + srow) * outld + o0] = pk;
    } else {
      #pragma unroll
      for (int r = 0; r < 4; ++r)
        dstF[((size_t)b * rows + o0 + r) * MM + srow] = v[r];
    }
  }
}

// ---------------- f/g BN stats partials over FGraw (B,MM,64) f32 ----------------
__global__ __launch_bounds__(256) void k_fgstats(const float* __restrict__ FGraw,
                                                 float* __restrict__ FGP) {
  __shared__ float red[4][64][2];
  int t = threadIdx.x; int c = t & 63, rq = t >> 6;
  int blk = blockIdx.x;
  float s = 0.f, s2 = 0.f;
  for (int k = 0; k < 64; ++k) {
    int r = blk * 256 + rq + 4 * k;
    float v = FGraw[(size_t)r * 64 + c];
    s += v; s2 += v * v;
  }
  red[rq][c][0] = s; red[rq][c][1] = s2;
  __syncthreads();
  if (t < 64) {
    float a = 0.f, a2 = 0.f;
    #pragma unroll
    for (int q = 0; q < 4; ++q) { a += red[q][t][0]; a2 += red[q][t][1]; }
    FGP[((size_t)blk * 64 + t) * 2] = a; FGP[((size_t)blk * 64 + t) * 2 + 1] = a2;
  }
}

__global__ __launch_bounds__(64) void k_fgfin(const float* __restrict__ FGP,
                                              const float* __restrict__ gf, const float* __restrict__ bef,
                                              const float* __restrict__ gg, const float* __restrict__ beg,
                                              float* __restrict__ ab) {
  int c = threadIdx.x;
  float s = 0.f, s2 = 0.f;
  for (int blk = 0; blk < 64; ++blk) { s += FGP[((size_t)blk * 64 + c) * 2]; s2 += FGP[((size_t)blk * 64 + c) * 2 + 1]; }
  float cnt = 16384.f;
  float mean = s / cnt, var = s2 / cnt - mean * mean;
  float gv = (c < 32) ? gf[c] : gg[c - 32];
  float bv = (c < 32) ? bef[c] : beg[c - 32];
  float alpha = gv * rsqrtf(var + EPSBN);
  ab[c * 2] = alpha; ab[c * 2 + 1] = bv - mean * alpha;
}

// ---------------- H BN stats (f32 ch-major) ----------------
__global__ __launch_bounds__(256) void k_bnstats(const float* __restrict__ src,
                                                 const float* __restrict__ g,
                                                 const float* __restrict__ be,
                                                 float* __restrict__ ab, int ldC) {
  int o = blockIdx.x;
  int t = threadIdx.x;
  float s = 0.f, s2 = 0.f;
  for (int b = 0; b < NB; ++b) {
    const float* r = src + ((size_t)b * ldC + o) * MM;
    for (int m = t; m < MM; m += 256) { float v = r[m]; s += v; s2 += v * v; }
  }
  __shared__ float rs[256], rs2[256];
  rs[t] = s; rs2[t] = s2;
  __syncthreads();
  for (int off = 128; off > 0; off >>= 1) {
    if (t < off) { rs[t] += rs[t + off]; rs2[t] += rs2[t + off]; }
    __syncthreads();
  }
  if (t == 0) {
    float cnt = 16384.0f;
    float mean = rs[0] / cnt, var = rs2[0] / cnt - mean * mean;
    float alpha = g[o] * rsqrtf(var + EPSBN);
    ab[o * 2] = alpha; ab[o * 2 + 1] = be[o] - mean * alpha;
  }
}

// ---------------- cvt FGraw -> FGT bf16 (BN+relu; F channels pre-scaled by LOG2E) ----------------
__global__ __launch_bounds__(256) void k_cvtFG(const float* __restrict__ FGraw,
                                               const float* __restrict__ ab,
                                               unsigned short* __restrict__ FGT) {
  int i = blockIdx.x * 256 + threadIdx.x;  // < 131072
  int row = i >> 3, c0 = (i & 7) * 8;
  float sc = (c0 < 32) ? LOG2E : 1.0f;
  float vv[8];
  float4 u0 = *(const float4*)&FGraw[(size_t)row * 64 + c0];
  float4 u1 = *(const float4*)&FGraw[(size_t)row * 64 + c0 + 4];
  vv[0] = u0.x; vv[1] = u0.y; vv[2] = u0.z; vv[3] = u0.w;
  vv[4] = u1.x; vv[5] = u1.y; vv[6] = u1.z; vv[7] = u1.w;
  uint4 pk;
  unsigned pw[4];
  #pragma unroll
  for (int h = 0; h < 4; ++h) {
    int c = c0 + 2 * h;
    float a0 = ab[c * 2] * sc, b0 = ab[c * 2 + 1] * sc;
    float a1 = ab[(c + 1) * 2] * sc, b1 = ab[(c + 1) * 2 + 1] * sc;
    float x0 = fmaxf(fmaf(a0, vv[2 * h], b0), 0.f);
    float x1 = fmaxf(fmaf(a1, vv[2 * h + 1], b1), 0.f);
    pw[h] = cvtpk(x0, x1);
  }
  pk.x = pw[0]; pk.y = pw[1]; pk.z = pw[2]; pk.w = pw[3];
  *(uint4*)&FGT[(size_t)row * 64 + c0] = pk;
}

// ---------------- cvt Hraw -> HB bf16 (BN+relu, ch-major, zero pad) ----------------
__global__ __launch_bounds__(256) void k_cvtH(const float* __restrict__ src,
                                              const float* __restrict__ ab,
                                              unsigned short* __restrict__ dst) {
  int i = blockIdx.x * 256 + threadIdx.x;  // (b*144 + c)*1024 + m4
  int m4 = i & 1023; int c = (i >> 10) % 144; int b = i / (144 * 1024);
  ushort4 ov = {0, 0, 0, 0};
  if (c < 130) {
    float4 v = *(const float4*)&src[((size_t)b * 144 + c) * MM + m4 * 4];
    float a = ab[c * 2], be = ab[c * 2 + 1];
    ov.x = f2bf(fmaxf(fmaf(a, v.x, be), 0.f));
    ov.y = f2bf(fmaxf(fmaf(a, v.y, be), 0.f));
    ov.z = f2bf(fmaxf(fmaf(a, v.z, be), 0.f));
    ov.w = f2bf(fmaxf(fmaf(a, v.w, be), 0.f));
  }
  *(ushort4*)&dst[((size_t)b * 144 + c) * MM + m4 * 4] = ov;
}

// ---------------- K-LSE: S in log2 domain (F pre-scaled); defer-max online ----------------
__global__ __launch_bounds__(256) void k_zlse(const unsigned short* __restrict__ FGT,
                                              float* __restrict__ LSEP) {
  int t = threadIdx.x; int w = t >> 6; int l = t & 63;
  int b = blockIdx.z; int ms = blockIdx.y;
  int n0 = blockIdx.x * 64 + w * 16;
  int lm = l & 15, g = l >> 4;
  f32x4 z4 = {0.f, 0.f, 0.f, 0.f};
  short8 af = *(const short8*)&FGT[((size_t)b * MM + n0 + lm) * 64 + 32 + 8 * g];
  float rm[4], zz[4];
  #pragma unroll
  for (int r = 0; r < 4; ++r) { rm[r] = -__builtin_inff(); zz[r] = 0.f; }
  for (int it = 0; it < 16; ++it) {
    int m0 = ms * 1024 + it * 64;
    short8 bfr[4];
    #pragma unroll
    for (int mi = 0; mi < 4; ++mi)
      bfr[mi] = *(const short8*)&FGT[((size_t)b * MM + m0 + mi * 16 + lm) * 64 + 8 * g];
    f32x4 d[4];
    #pragma unroll
    for (int mi = 0; mi < 4; ++mi) d[mi] = MFMA16(af, bfr[mi], z4);
    #pragma unroll
    for (int r = 0; r < 4; ++r) {
      float tm = fmaxf(fmaxf(d[0][r], d[1][r]), fmaxf(d[2][r], d[3][r]));
      float nm = fmaxf(rm[r], tm);
      zz[r] = zz[r] * exp2f(rm[r] - nm)
            + exp2f(d[0][r] - nm) + exp2f(d[1][r] - nm)
            + exp2f(d[2][r] - nm) + exp2f(d[3][r] - nm);
      rm[r] = nm;
    }
  }
  #pragma unroll
  for (int off = 1; off < 16; off <<= 1) {
    #pragma unroll
    for (int r = 0; r < 4; ++r) {
      float om = __shfl_xor(rm[r], off);
      float oz = __shfl_xor(zz[r], off);
      float nm = fmaxf(rm[r], om);
      zz[r] = zz[r] * exp2f(rm[r] - nm) + oz * exp2f(om - nm);
      rm[r] = nm;
    }
  }
  if (lm == 0) {
    #pragma unroll
    for (int r = 0; r < 4; ++r) {
      int n = n0 + 4 * g + r;
      size_t idx = ((size_t)ms * 16384 + (size_t)b * MM + n) * 2;
      LSEP[idx] = rm[r]; LSEP[idx + 1] = zz[r];
    }
  }
}

// ---------------- merge LSE partials ----------------
__global__ __launch_bounds__(256) void k_lsered(const float* __restrict__ LSEP,
                                                float* __restrict__ LSE) {
  int bn = blockIdx.x * 256 + threadIdx.x;  // < 16384
  float rm = -__builtin_inff(), zz = 0.f;
  #pragma unroll
  for (int ms = 0; ms < 4; ++ms) {
    float m = LSEP[((size_t)ms * 16384 + bn) * 2];
    float z = LSEP[((size_t)ms * 16384 + bn) * 2 + 1];
    float nm = fmaxf(rm, m);
    zz = zz * exp2f(rm - nm) + z * exp2f(m - nm);
    rm = nm;
  }
  LSE[bn] = rm + log2f(zz);
}

// ---------------- K-O: MFMA O-pass, LDS-staged H (reg-staged async double buffer) ----------------
// grid (32 mblocks, 4 b, 6 splits), 256 thr (4 waves). H chunk (144ch x 32n bf16)
// staged once per block into LDS (rows padded 64->80B), shared by all 4 waves.
__global__ __launch_bounds__(256) void k_omfma(const unsigned short* __restrict__ FGT,
                                               const unsigned short* __restrict__ HB,
                                               const float* __restrict__ LSE,
                                               unsigned short* __restrict__ Opart) {
  __shared__ __align__(16) unsigned short Hs[2][144 * 40];  // 2 x 11520 B
  int t = threadIdx.x; int w = t >> 6; int l = t & 63;
  int b = blockIdx.y; int split = blockIdx.z;
  int lm = l & 15, g = l >> 4;
  int mcol0 = blockIdx.x * 128 + w * 32 + lm;
  int mcol1 = mcol0 + 16;
  f32x4 z4 = {0.f, 0.f, 0.f, 0.f};
  short8 Ff0 = *(const short8*)&FGT[((size_t)b * MM + mcol0) * 64 + 8 * g];
  short8 Ff1 = *(const short8*)&FGT[((size_t)b * MM + mcol1) * 64 + 8 * g];
  f32x4 acc0[9], acc1[9];
  #pragma unroll
  for (int ct = 0; ct < 9; ++ct) { acc0[ct] = z4; acc1[ct] = z4; }
  const int nchunks = (split < 2) ? 22 : 21;
  const int startc = split * 21 + ((split < 2) ? split : 2);
  const int start = startc * 32;
  const unsigned short* gptr = FGT + ((size_t)b * MM + lm) * 64 + 32 + 8 * g;
  const unsigned short* hsrc = HB + (size_t)b * 144 * MM;
  const float* lbase = LSE + (size_t)b * MM + 4 * g;
  int src01 = lm + 16 * (2 * (g & 1));
  int src23 = src01 + 16;
  bool hi = g >= 2;
  // staging indices for this thread (3 slots, 576 total items)
  int sidx0 = t, sidx1 = t + 256, sidx2 = t + 512;
  int ch0 = sidx0 >> 2, sg0 = sidx0 & 3;
  int ch1 = sidx1 >> 2, sg1 = sidx1 & 3;
  int ch2 = (sidx2 < 576) ? (sidx2 >> 2) : 0;
  int sg2 = sidx2 & 3;
  bool has2 = sidx2 < 576;

  // preamble: stage chunk 0 into buf 0
  {
    uint4 r0 = *(const uint4*)(hsrc + (size_t)ch0 * MM + start + sg0 * 8);
    uint4 r1 = *(const uint4*)(hsrc + (size_t)ch1 * MM + start + sg1 * 8);
    uint4 r2 = has2 ? *(const uint4*)(hsrc + (size_t)ch2 * MM + start + sg2 * 8) : uint4{0,0,0,0};
    *(uint4*)&Hs[0][ch0 * 40 + sg0 * 8] = r0;
    *(uint4*)&Hs[0][ch1 * 40 + sg1 * 8] = r1;
    if (has2) *(uint4*)&Hs[0][ch2 * 40 + sg2 * 8] = r2;
  }
  // G/LSE for chunk 0
  short8 a0 = *(const short8*)(gptr + (size_t)start * 64);
  short8 a1 = *(const short8*)(gptr + (size_t)(start + 16) * 64);
  float4 l0 = *(const float4*)(lbase + start);
  float4 l1 = *(const float4*)(lbase + start + 16);
  __syncthreads();

  for (int it = 0; it < nchunks; ++it) {
    int n0 = start + it * 32;
    int cur = it & 1;
    bool more = (it + 1 < nchunks);
    int n1 = more ? (n0 + 32) : start;
    // (A) issue global loads for NEXT H chunk into regs (latency hides under compute)
    uint4 r0, r1, r2;
    if (more) {
      r0 = *(const uint4*)(hsrc + (size_t)ch0 * MM + n1 + sg0 * 8);
      r1 = *(const uint4*)(hsrc + (size_t)ch1 * MM + n1 + sg1 * 8);
      if (has2) r2 = *(const uint4*)(hsrc + (size_t)ch2 * MM + n1 + sg2 * 8);
    }
    // next G/LSE into regs
    short8 na0 = *(const short8*)(gptr + (size_t)n1 * 64);
    short8 na1 = *(const short8*)(gptr + (size_t)(n1 + 16) * 64);
    float4 nl0 = *(const float4*)(lbase + n1);
    float4 nl1 = *(const float4*)(lbase + n1 + 16);
    // (B) compute current chunk from LDS buf[cur]
    short8 hf[9];
    #pragma unroll
    for (int ct = 0; ct < 9; ++ct)
      hf[ct] = *(const short8*)&Hs[cur][(lm + 16 * ct) * 40 + g * 8];
    f32x4 s00 = MFMA16(a0, Ff0, z4);
    f32x4 s10 = MFMA16(a1, Ff0, z4);
    f32x4 s01 = MFMA16(a0, Ff1, z4);
    f32x4 s11 = MFMA16(a1, Ff1, z4);
    float le0[4] = {l0.x, l0.y, l0.z, l0.w};
    float le1[4] = {l1.x, l1.y, l1.z, l1.w};
    unsigned pk00[2], pk10[2], pk01[2], pk11[2];
    #pragma unroll
    for (int h2 = 0; h2 < 2; ++h2) {
      pk00[h2] = cvtpk(exp2f(s00[2*h2] - le0[2*h2]), exp2f(s00[2*h2+1] - le0[2*h2+1]));
      pk10[h2] = cvtpk(exp2f(s10[2*h2] - le1[2*h2]), exp2f(s10[2*h2+1] - le1[2*h2+1]));
      pk01[h2] = cvtpk(exp2f(s01[2*h2] - le0[2*h2]), exp2f(s01[2*h2+1] - le0[2*h2+1]));
      pk11[h2] = cvtpk(exp2f(s11[2*h2] - le1[2*h2]), exp2f(s11[2*h2+1] - le1[2*h2+1]));
    }
    unsigned a0w = (unsigned)__shfl((int)pk00[0], src01);
    unsigned b0w = (unsigned)__shfl((int)pk10[0], src01);
    unsigned a1w = (unsigned)__shfl((int)pk00[1], src01);
    unsigned b1w = (unsigned)__shfl((int)pk10[1], src01);
    unsigned a2w = (unsigned)__shfl((int)pk00[0], src23);
    unsigned b2w = (unsigned)__shfl((int)pk10[0], src23);
    unsigned a3w = (unsigned)__shfl((int)pk00[1], src23);
    unsigned b3w = (unsigned)__shfl((int)pk10[1], src23);
    union { unsigned u[4]; short8 s; } bu0;
    bu0.u[0] = hi ? b0w : a0w; bu0.u[1] = hi ? b1w : a1w;
    bu0.u[2] = hi ? b2w : a2w; bu0.u[3] = hi ? b3w : a3w;
    short8 bfrag0 = bu0.s;
    unsigned c0w = (unsigned)__shfl((int)pk01[0], src01);
    unsigned d0w = (unsigned)__shfl((int)pk11[0], src01);
    unsigned c1w = (unsigned)__shfl((int)pk01[1], src01);
    unsigned d1w = (unsigned)__shfl((int)pk11[1], src01);
    unsigned c2w = (unsigned)__shfl((int)pk01[0], src23);
    unsigned d2w = (unsigned)__shfl((int)pk11[0], src23);
    unsigned c3w = (unsigned)__shfl((int)pk01[1], src23);
    unsigned d3w = (unsigned)__shfl((int)pk11[1], src23);
    union { unsigned u[4]; short8 s; } bu1;
    bu1.u[0] = hi ? d0w : c0w; bu1.u[1] = hi ? d1w : c1w;
    bu1.u[2] = hi ? d2w : c2w; bu1.u[3] = hi ? d3w : c3w;
    short8 bfrag1 = bu1.s;
    __builtin_amdgcn_s_setprio(1);
    #pragma unroll
    for (int ct = 0; ct < 9; ++ct) {
      acc0[ct] = MFMA16(hf[ct], bfrag0, acc0[ct]);
      acc1[ct] = MFMA16(hf[ct], bfrag1, acc1[ct]);
    }
    __builtin_amdgcn_s_setprio(0);
    // (C) write staged regs into the other buffer, (D) barrier
    if (more) {
      *(uint4*)&Hs[cur ^ 1][ch0 * 40 + sg0 * 8] = r0;
      *(uint4*)&Hs[cur ^ 1][ch1 * 40 + sg1 * 8] = r1;
      if (has2) *(uint4*)&Hs[cur ^ 1][ch2 * 40 + sg2 * 8] = r2;
    }
    a0 = na0; a1 = na1; l0 = nl0; l1 = nl1;
    __syncthreads();
  }

  unsigned short* op0 = Opart + (size_t)split * OPS_SH + ((size_t)b * MM + mcol0) * 132;
  unsigned short* op1 = Opart + (size_t)split * OPS_SH + ((size_t)b * MM + mcol1) * 132;
  #pragma unroll
  for (int ct = 0; ct < 9; ++ct) {
    int c0 = ct * 16 + 4 * g;
    if (c0 < 132) {
      uint2 p0, p1;
      p0.x = cvtpk(acc0[ct][0], acc0[ct][1]);
      p0.y = cvtpk(acc0[ct][2], acc0[ct][3]);
      p1.x = cvtpk(acc1[ct][0], acc1[ct][1]);
      p1.y = cvtpk(acc1[ct][2], acc1[ct][3]);
      *(uint2*)&op0[c0] = p0;
      *(uint2*)&op1[c0] = p1;
    }
  }
}

// ---------------- O reduce: A16 = bf16(gamma*sum(Oparts) + X) ----------------
__global__ __launch_bounds__(256) void k_ored(const unsigned short* __restrict__ Op,
                                              const unsigned short* __restrict__ X16,
                                              const float* __restrict__ gma,
                                              unsigned short* __restrict__ A16) {
  int i = blockIdx.x * 256 + threadIdx.x;  // < 327680
  int row = i / 20, c8 = i % 20;
  int c0 = c8 * 8;
  unsigned short* ap = A16 + (size_t)row * 160 + c0;
  if (c0 >= 136) {
    uint4 z = {0, 0, 0, 0};
    *(uint4*)ap = z;
    return;
  }
  float gm = gma[0];
  float ov[8] = {0.f, 0.f, 0.f, 0.f, 0.f, 0.f, 0.f, 0.f};
  #pragma unroll
  for (int s = 0; s < 6; ++s) {
    const unsigned short* base = Op + (size_t)s * OPS_SH + (size_t)row * 132 + c0;
    uint2 u = *(const uint2*)base;
    ov[0] += bf2f((unsigned short)(u.x & 0xffff));
    ov[1] += bf2f((unsigned short)(u.x >> 16));
    ov[2] += bf2f((unsigned short)(u.y & 0xffff));
    ov[3] += bf2f((unsigned short)(u.y >> 16));
    if (c0 + 4 < 132) {
      uint2 v = *(const uint2*)(base + 4);
      ov[4] += bf2f((unsigned short)(v.x & 0xffff));
      ov[5] += bf2f((unsigned short)(v.x >> 16));
      ov[6] += bf2f((unsigned short)(v.y & 0xffff));
      ov[7] += bf2f((unsigned short)(v.y >> 16));
    }
  }
  short8 xv = *(const short8*)(X16 + (size_t)row * 160 + c0);
  unsigned pw[4];
  #pragma unroll
  for (int h = 0; h < 4; ++h) {
    int ca = c0 + 2 * h, cb = c0 + 2 * h + 1;
    float xa = bf2f((unsigned short)xv[2 * h]);
    float xb = bf2f((unsigned short)xv[2 * h + 1]);
    float va = (ca < 132) ? (gm * ov[2 * h] + xa) : 0.f;
    float vb = (cb < 132) ? (gm * ov[2 * h + 1] + xb) : 0.f;
    pw[h] = (unsigned)f2bf(va) | ((unsigned)f2bf(vb) << 16);
  }
  uint4 pk = {pw[0], pw[1], pw[2], pw[3]};
  *(uint4*)ap = pk;
}

extern "C" void kernel_launch(void* const* d_in, const int* in_sizes, int n_in,
                              void* d_out, int out_size, void* d_ws, size_t ws_size,
                              hipStream_t stream) {
  const float* inp = (const float*)d_in[0];
  const float* Wa  = (const float*)d_in[1];
  const float* gna = (const float*)d_in[2];
  const float* bta = (const float*)d_in[3];
  const float* Wb  = (const float*)d_in[4];
  const float* gnb = (const float*)d_in[5];
  const float* btb = (const float*)d_in[6];
  const float* Wf  = (const float*)d_in[7];
  const float* bf  = (const float*)d_in[8];
  const float* gf  = (const float*)d_in[9];
  const float* bef = (const float*)d_in[10];
  const float* Wg  = (const float*)d_in[11];
  const float* bg  = (const float*)d_in[12];
  const float* gg  = (const float*)d_in[13];
  const float* beg = (const float*)d_in[14];
  const float* Wh  = (const float*)d_in[15];
  const float* bh  = (const float*)d_in[16];
  const float* gh  = (const float*)d_in[17];
  const float* beh = (const float*)d_in[18];
  const float* gamma = (const float*)d_in[19];
  const float* W1  = (const float*)d_in[20];
  const float* b1  = (const float*)d_in[21];
  const float* W2  = (const float*)d_in[22];
  const float* b2  = (const float*)d_in[23];
  float* out = (float*)d_out;

  float* ws = (float*)d_ws;
  float* DIST = ws + OFF_DIST;
  float* PM   = ws + OFF_PM;
  float* QM   = ws + OFF_QM;
  float* HRAW = ws + OFF_HRAW;
  float* FGRAW= ws + OFF_FGRAW;
  unsigned short* OP16 = (unsigned short*)(ws + OFF_OP);
  unsigned short* FGT = (unsigned short*)(ws + OFF_FGT);
  unsigned short* HBB = (unsigned short*)(ws + OFF_HB);
  unsigned short* A16 = (unsigned short*)(ws + OFF_A16);
  unsigned short* X16 = (unsigned short*)(ws + OFF_X16);
  unsigned short* Y1  = (unsigned short*)(ws + OFF_Y1);
  float* LSEB = ws + OFF_LSE;
  float* LSEP = ws + OFF_LSEP;
  float* STATS= ws + OFF_STATS;
  float* ABE  = ws + OFF_ABE;
  float* ABFG = ws + OFF_ABFG;
  float* ABH  = ws + OFF_ABH;
  float* FGP  = ws + OFF_FGP;
  float* BIAS = ws + OFF_BIAS;
  unsigned short* W16 = (unsigned short*)(ws + OFF_W16);
  int*   KNNI = (int*)(ws + OFF_KNN);
  float* XN   = ws + OFF_XN;
  unsigned short* XR = (unsigned short*)(ws + OFF_XR);
  unsigned short* WPQ = (unsigned short*)(ws + OFF_WPQ);
  float* SQ   = ws + OFF_SQ;

  // 0. weight prep (merged)
  k_prep<<<933, 256, 0, stream>>>(Wf, Wg, Wh, W1, W2, bf, bg, bh, b1, b2, Wa, Wb, W16, BIAS, WPQ);
  // 1-3. normalize (fp32 XN + bf16 XR), fp32 dist 128x128 (exact kNN path), knn
  k_norm<<<16, 256, 0, stream>>>(inp, XN, XR, SQ);
  k_dist<<<dim3(8, 8, 4), 256, 0, stream>>>(XN, SQ, DIST);
  k_knn<<<4096, 64, 0, stream>>>(DIST, KNNI);
  // 4. P/Q MFMA (overwrites DIST) ; 5-6. edge BN ; 7. apply -> X16
  k_pqm<<<dim3(16, 4, 8), 256, 0, stream>>>(XR, WPQ, PM, QM);
  k_edge_stats<<<dim3(16, 4, 2), 256, 0, stream>>>(PM, QM, KNNI, STATS);
  k_edge_fin<<<2, 256, 0, stream>>>(STATS, gna, bta, gnb, btb, ABE);
  k_edge_apply<<<dim3(1024, 4), 256, 0, stream>>>(PM, QM, KNNI, ABE, X16);
  // 8. f+g conv (f32 m-major raw) and h conv (f32 ch-major raw), over dead PM/QM region
  k_convm<5, 2, 0, false><<<dim3(64, 2, 4), 256, 0, stream>>>(X16, W16 + W16_FG, BIAS + B_FG, FGRAW, nullptr, 64, 0);
  k_convm<5, 3, 2, false><<<dim3(64, 3, 4), 256, 0, stream>>>(X16, W16 + W16_H, BIAS + B_H, HRAW, nullptr, 0, 144);
  // 9. BN stats + fused apply/cvt to bf16
  k_fgstats<<<64, 256, 0, stream>>>(FGRAW, FGP);
  k_fgfin<<<1, 64, 0, stream>>>(FGP, gf, bef, gg, beg, ABFG);
  k_bnstats<<<130, 256, 0, stream>>>(HRAW, gh, beh, ABH, 144);
  k_cvtFG<<<512, 256, 0, stream>>>(FGRAW, ABFG, FGT);
  k_cvtH<<<2304, 256, 0, stream>>>(HRAW, ABH, HBB);
  // 10. LSE ; 11. O-pass (LDS-staged H double buffer) ; 12. reduce -> A16
  k_zlse<<<dim3(64, 4, 4), 256, 0, stream>>>(FGT, LSEP);
  k_lsered<<<64, 256, 0, stream>>>(LSEP, LSEB);
  k_omfma<<<dim3(32, 4, 6), 256, 0, stream>>>(FGT, HBB, LSEB, OP16);
  k_ored<<<1280, 256, 0, stream>>>(OP16, X16, gamma, A16);
  // 13-14. final convs (MFMA)
  k_convm<5, 8, 1, true><<<dim3(64, 2, 4), 256, 0, stream>>>(A16, W16 + W16_C1, BIAS + B_C1, nullptr, Y1, 256, 0);
  k_convm<8, 4, 2, true><<<dim3(64, 2, 4), 256, 0, stream>>>(Y1, W16 + W16_C2, BIAS + B_C2, out, nullptr, 0, 128);
}

// Round 13
// 313.181 us; speedup vs baseline: 1.0133x; 1.0133x over previous
//
#include <hip/hip_runtime.h>

namespace {
constexpr int NB = 4;      // batch
constexpr int CI = 128;    // input channels
constexpr int NP = 1024;   // points
constexpr int MM = 4096;   // N*UP
constexpr float EPSBN = 1e-5f;
constexpr float LOG2E = 1.4426950408889634f;

constexpr size_t OPS_SH = 2162688;       // Opart split stride in SHORTS (B*MM*132)
// workspace offsets (floats)
constexpr size_t OFF_OP   = 0;           // 6 bf16 splits = 6488064 floats (overlaid: DIST / Pm,Qm / Hraw,FGraw / Y1)
constexpr size_t OFF_DIST = 0;           // 4194304
constexpr size_t OFF_PM   = 0;           // 2097152
constexpr size_t OFF_QM   = 2097152;     // 2097152
constexpr size_t OFF_HRAW = 0;           // 2359296 (B,144,MM) f32
constexpr size_t OFF_FGRAW= 2359296;     // 1048576 (B,MM,64) f32  -> ends 3407872
constexpr size_t OFF_Y1   = 0;           // (B,MM,256) bf16 = 2097152 floats
constexpr size_t OFF_FGT  = 6488064;     // (B,MM,64) bf16 = 524288 floats
constexpr size_t OFF_HB   = 7012352;     // (B,144,MM) bf16 = 1179648 floats
constexpr size_t OFF_A16  = 6488064;     // (B,MM,160) bf16 = 1310720 floats (over FGT/HB after omfma)
constexpr size_t OFF_X16  = 8192000;     // (B,MM,160) bf16 = 1310720 floats
constexpr size_t OFF_LSE  = 9502720;     // 16384
constexpr size_t OFF_LSEP = 9519104;     // 131072
constexpr size_t OFF_STATS= 9650176;     // 65536
constexpr size_t OFF_ABE  = 9715712;     // 1024
constexpr size_t OFF_ABFG = 9716736;     // 128 (unused now)
constexpr size_t OFF_ABH  = 9716864;     // 512
constexpr size_t OFF_FGP  = 9717376;     // 8192
constexpr size_t OFF_BIAS = 9725568;     // 640
constexpr size_t OFF_W16  = 9726208;     // 53504 (107008 shorts)
constexpr size_t OFF_KNN  = 9779712;     // 73728 ints
constexpr size_t OFF_XN   = 9853440;     // (B,128,1024) f32 = 524288 (normalized, ch-major, for fp32 dist)
constexpr size_t OFF_SQ   = 10377728;    // 4096
constexpr size_t OFF_XR   = 10381824;    // (B,1024,128) bf16 raw = 262144 floats
constexpr size_t OFF_WPQ  = 10643968;    // 65536 floats (131072 shorts) -> ends 10709504
// W16 sub-offsets (shorts)
constexpr size_t W16_FG = 0;       // 64x160
constexpr size_t W16_H  = 10240;   // 144x160
constexpr size_t W16_C1 = 33280;   // 256x160
constexpr size_t W16_C2 = 74240;   // 128x256
// BIAS sub-offsets (floats)
constexpr size_t B_FG = 0, B_H = 64, B_C1 = 208, B_C2 = 464;
} // namespace

typedef __attribute__((ext_vector_type(8))) short short8;
typedef __attribute__((ext_vector_type(4))) float f32x4;
#define MFMA16(A, B, C) __builtin_amdgcn_mfma_f32_16x16x32_bf16(A, B, C, 0, 0, 0)

__device__ inline unsigned short f2bf(float x) {
  unsigned int u = __float_as_uint(x);
  unsigned int r = u + 0x7fff + ((u >> 16) & 1);
  return (unsigned short)(r >> 16);
}
__device__ inline float bf2f(unsigned short s) {
  return __uint_as_float(((unsigned int)s) << 16);
}
__device__ inline unsigned cvtpk(float lo, float hi) {
  unsigned r;
  asm("v_cvt_pk_bf16_f32 %0, %1, %2" : "=v"(r) : "v"(lo), "v"(hi));
  return r;
}

// ---------------- K0: fused weight-prep + normalize ----------------
// blocks 0..932: prep (W16/BIAS/WPQ). blocks 933..948: norm (XN/XR/SQ).
__global__ __launch_bounds__(256) void k_init(const float* __restrict__ Wf, const float* __restrict__ Wg,
                                              const float* __restrict__ Wh, const float* __restrict__ W1,
                                              const float* __restrict__ W2, const float* __restrict__ bf,
                                              const float* __restrict__ bg, const float* __restrict__ bh,
                                              const float* __restrict__ b1, const float* __restrict__ b2,
                                              const float* __restrict__ Wa, const float* __restrict__ Wb,
                                              unsigned short* __restrict__ W16, float* __restrict__ BIAS,
                                              unsigned short* __restrict__ WPQ,
                                              const float* __restrict__ x,
                                              float* __restrict__ xn,
                                              unsigned short* __restrict__ XR,
                                              float* __restrict__ sq) {
  if (blockIdx.x < 933) {
    int i = blockIdx.x * 256 + threadIdx.x;
    if (i < 107008) {
      float v = 0.f;
      if (i < 10240) { int o = i / 160, c = i % 160; if (c < 130) v = (o < 32) ? Wf[o * 130 + c] : Wg[(o - 32) * 130 + c]; }
      else if (i < 33280) { int r = i - 10240; int o = r / 160, c = r % 160; if (o < 130 && c < 130) v = Wh[o * 130 + c]; }
      else if (i < 74240) { int r = i - 33280; int o = r / 160, c = r % 160; if (c < 130) v = W1[o * 130 + c]; }
      else { int r = i - 74240; int o = r / 256, c = r % 256; v = W2[o * 256 + c]; }
      W16[i] = f2bf(v);
    } else if (i < 107648) {
      int j = i - 107008; float v = 0.f;
      if (j < 64) v = (j < 32) ? bf[j] : bg[j - 32];
      else if (j < 208) { int c = j - 64; if (c < 130) v = bh[c]; }
      else if (j < 464) v = b1[j - 208];
      else if (j < 592) v = b2[j - 464];
      BIAS[j] = v;
    } else if (i < 238720) {
      int j = i - 107648;
      int e = j >> 16;
      int rem = j & 65535;
      int pq = rem >> 15;
      int rr = rem & 32767;
      int o = rr >> 7, c = rr & 127;
      const float* W = e ? Wb : Wa;
      float w1 = W[o * 256 + c], w2 = W[o * 256 + 128 + c];
      float v = pq ? w2 : (w1 - w2);
      WPQ[j] = f2bf(v);
    }
  } else {
    int t = (blockIdx.x - 933) * 256 + threadIdx.x;   // b*1024+n
    int b = t >> 10, n = t & 1023;
    const float* xb = x + (size_t)b * CI * NP + n;
    float ss = 0.f;
    #pragma unroll 4
    for (int c = 0; c < CI; ++c) { float v = xb[(size_t)c * NP]; ss += v * v; }
    float inv = 1.f / fmaxf(sqrtf(ss), 1e-12f);
    float* xo = xn + (size_t)b * CI * NP + n;
    float s2 = 0.f;
    for (int c0 = 0; c0 < 128; c0 += 8) {
      unsigned rw[4];
      #pragma unroll
      for (int j = 0; j < 4; ++j) {
        float va = xb[(size_t)(c0 + 2 * j) * NP];
        float vb = xb[(size_t)(c0 + 2 * j + 1) * NP];
        float na = va * inv, nb = vb * inv;
        s2 += na * na + nb * nb;
        xo[(size_t)(c0 + 2 * j) * NP] = na;
        xo[(size_t)(c0 + 2 * j + 1) * NP] = nb;
        rw[j] = (unsigned)f2bf(va) | ((unsigned)f2bf(vb) << 16);
      }
      uint4 r4 = {rw[0], rw[1], rw[2], rw[3]};
      *(uint4*)&XR[(size_t)t * 128 + c0] = r4;
    }
    sq[t] = s2;
  }
}

// ---------------- K2: pairwise distance, fp32 128x64 tile (exact kNN path; same fp order) ----------------
// grid (16 mtiles, 8 ntiles, 4 b), 256 thr; each thread 8n x 4m outputs
__global__ __launch_bounds__(256) void k_dist(const float* __restrict__ xn,
                                              const float* __restrict__ sq,
                                              float* __restrict__ dist) {
  __shared__ float As[32][132], Bs[32][68];
  int t = threadIdx.x;
  int m0 = blockIdx.x * 64, n0 = blockIdx.y * 128, b = blockIdx.z;
  int mg = t & 15, ng = t >> 4;
  float acc[8][4];
  #pragma unroll
  for (int i = 0; i < 8; ++i)
    #pragma unroll
    for (int j = 0; j < 4; ++j) acc[i][j] = 0.f;
  for (int cc = 0; cc < 128; cc += 32) {
    __syncthreads();
    for (int idx = t; idx < 4096; idx += 256) {
      int c = idx >> 7, j = idx & 127;
      As[c][j] = xn[((size_t)b * CI + cc + c) * NP + n0 + j];
    }
    for (int idx = t; idx < 2048; idx += 256) {
      int c = idx >> 6, j = idx & 63;
      Bs[c][j] = xn[((size_t)b * CI + cc + c) * NP + m0 + j];
    }
    __syncthreads();
    #pragma unroll
    for (int c = 0; c < 32; ++c) {
      float4 a0 = *(const float4*)&As[c][ng * 8];
      float4 a1 = *(const float4*)&As[c][ng * 8 + 4];
      float4 b0 = *(const float4*)&Bs[c][mg * 4];
      float av[8] = {a0.x, a0.y, a0.z, a0.w, a1.x, a1.y, a1.z, a1.w};
      float bv[4] = {b0.x, b0.y, b0.z, b0.w};
      #pragma unroll
      for (int i = 0; i < 8; ++i)
        #pragma unroll
        for (int j = 0; j < 4; ++j) acc[i][j] += av[i] * bv[j];
    }
  }
  #pragma unroll
  for (int i = 0; i < 8; ++i) {
    int n = n0 + ng * 8 + i;
    float sn = sq[b * NP + n];
    int mb = m0 + mg * 4;
    float4 r;
    r.x = sn + sq[b * NP + mb + 0] - 2.f * acc[i][0];
    r.y = sn + sq[b * NP + mb + 1] - 2.f * acc[i][1];
    r.z = sn + sq[b * NP + mb + 2] - 2.f * acc[i][2];
    r.w = sn + sq[b * NP + mb + 3] - 2.f * acc[i][3];
    *(float4*)&dist[((size_t)b * NP + n) * NP + mb] = r;
  }
}

// ---------------- K3: top-18 nearest per row ----------------
__global__ __launch_bounds__(64) void k_knn(const float* __restrict__ dist,
                                            int* __restrict__ knn) {
  int row = blockIdx.x;
  int l = threadIdx.x;
  const float* dr = dist + (size_t)row * NP;
  float d[16];
  #pragma unroll
  for (int i = 0; i < 16; ++i) d[i] = dr[l + 64 * i];
  for (int s = 0; s < 18; ++s) {
    float best = __builtin_inff(); int bslot = -1;
    #pragma unroll
    for (int i = 0; i < 16; ++i) if (d[i] < best) { best = d[i]; bslot = i; }
    int bidx = (bslot >= 0) ? (l + 64 * bslot) : 0x7fffffff;
    float bd = best; int bi = bidx;
    #pragma unroll
    for (int off = 32; off > 0; off >>= 1) {
      float od = __shfl_xor(bd, off);
      int   oi = __shfl_xor(bi, off);
      if (od < bd || (od == bd && oi < bi)) { bd = od; bi = oi; }
    }
    if (l == 0) knn[row * 18 + s] = bi;
    if ((bi & 63) == l) d[bi >> 6] = __builtin_inff();
  }
}

// ---------------- K4: P/Q pre-GEMMs via MFMA, m-major f32 out ----------------
__global__ __launch_bounds__(256) void k_pqm(const unsigned short* __restrict__ XR,
                                             const unsigned short* __restrict__ WPQ,
                                             float* __restrict__ Pm,
                                             float* __restrict__ Qm) {
  int t = threadIdx.x; int w = t >> 6; int l = t & 63;
  int lm = l & 15, g = l >> 4;
  int nt = blockIdx.x, oq = blockIdx.y, z = blockIdx.z;
  int e = z >> 2, b = z & 3;
  int srow = nt * 64 + w * 16 + lm;
  const unsigned short* sp = XR + ((size_t)b * 1024 + srow) * 128 + 8 * g;
  const unsigned short* wpp = WPQ + ((size_t)(e * 2 + 0) * 256 + oq * 64 + lm) * 128 + 8 * g;
  const unsigned short* wqq = WPQ + ((size_t)(e * 2 + 1) * 256 + oq * 64 + lm) * 128 + 8 * g;
  f32x4 accp[4], accq[4];
  #pragma unroll
  for (int i = 0; i < 4; ++i) { accp[i] = {0.f, 0.f, 0.f, 0.f}; accq[i] = {0.f, 0.f, 0.f, 0.f}; }
  #pragma unroll
  for (int cc = 0; cc < 4; ++cc) {
    short8 bfr = *(const short8*)(sp + cc * 32);
    #pragma unroll
    for (int ct = 0; ct < 4; ++ct) {
      short8 ap = *(const short8*)(wpp + (size_t)ct * 16 * 128 + cc * 32);
      accp[ct] = MFMA16(ap, bfr, accp[ct]);
      short8 aq = *(const short8*)(wqq + (size_t)ct * 16 * 128 + cc * 32);
      accq[ct] = MFMA16(aq, bfr, accq[ct]);
    }
  }
  int eb = e * 4 + b;
  #pragma unroll
  for (int ct = 0; ct < 4; ++ct) {
    int o0 = oq * 64 + ct * 16 + 4 * g;
    float4 rp = {accp[ct][0], accp[ct][1], accp[ct][2], accp[ct][3]};
    float4 rq = {accq[ct][0], accq[ct][1], accq[ct][2], accq[ct][3]};
    *(float4*)&Pm[((size_t)eb * 1024 + srow) * 256 + o0] = rp;
    *(float4*)&Qm[((size_t)eb * 1024 + srow) * 256 + o0] = rq;
  }
}

// ---------------- K5: edge BN stats partials ----------------
__global__ __launch_bounds__(256) void k_edge_stats(const float* __restrict__ Pm,
                                                    const float* __restrict__ Qm,
                                                    const int* __restrict__ knn,
                                                    float* __restrict__ stats) {
  int o = threadIdx.x;
  int chunk = blockIdx.x, b = blockIdx.y, e = blockIdx.z;
  int eb = e * 4 + b;
  float s = 0.f, s2 = 0.f;
  for (int nn = 0; nn < 64; ++nn) {
    int n = chunk * 64 + nn;
    float p = Pm[((size_t)eb * 1024 + n) * 256 + o];
    const int* kn = knn + (b * 1024 + n) * 18;
    #pragma unroll
    for (int kk = 0; kk < 9; ++kk) {
      int j = kn[e ? 2 * kk : kk];
      float v = p + Qm[((size_t)eb * 1024 + j) * 256 + o];
      s += v; s2 += v * v;
    }
  }
  size_t idx = ((((size_t)e * 4 + b) * 16 + chunk) * 256 + o) * 2;
  stats[idx] = s; stats[idx + 1] = s2;
}

// ---------------- K6: finalize edge BN ----------------
__global__ __launch_bounds__(256) void k_edge_fin(const float* __restrict__ stats,
                                                  const float* __restrict__ gna, const float* __restrict__ bta,
                                                  const float* __restrict__ gnb, const float* __restrict__ btb,
                                                  float* __restrict__ ab) {
  int i = blockIdx.x * 256 + threadIdx.x;
  if (i >= 512) return;
  int e = i >> 8, o = i & 255;
  float s = 0.f, s2 = 0.f;
  for (int b = 0; b < 4; ++b)
    for (int ch = 0; ch < 16; ++ch) {
      size_t idx = ((((size_t)e * 4 + b) * 16 + ch) * 256 + o) * 2;
      s += stats[idx]; s2 += stats[idx + 1];
    }
  float cnt = 4.0f * 1024.0f * 9.0f;
  float mean = s / cnt;
  float var = s2 / cnt - mean * mean;
  float g = e ? gnb[o] : gna[o];
  float bt = e ? btb[o] : bta[o];
  float alpha = g * rsqrtf(var + EPSBN);
  ab[i * 2] = alpha; ab[i * 2 + 1] = bt - mean * alpha;
}

// ---------------- K7: edge apply + max-over-k -> X16 (B,MM,160) bf16 ----------------
__global__ __launch_bounds__(256) void k_edge_apply(const float* __restrict__ Pm,
                                                    const float* __restrict__ Qm,
                                                    const int* __restrict__ knn,
                                                    const float* __restrict__ ab,
                                                    unsigned short* __restrict__ X16) {
  __shared__ int knl[18];
  int t = threadIdx.x;
  int n = blockIdx.x, b = blockIdx.y;
  if (t < 18) knl[t] = knn[(b * 1024 + n) * 18 + t];
  __syncthreads();
  int e = t >> 7, oo = t & 127;
  int eb = e * 4 + b;
  const float* Pr = Pm + ((size_t)eb * 1024 + n) * 256;
  const float* Qb = Qm + (size_t)eb * 1024 * 256;
  float p0 = Pr[oo], p1 = Pr[oo + 128];
  float a0 = ab[(e * 256 + oo) * 2], be0 = ab[(e * 256 + oo) * 2 + 1];
  float a1 = ab[(e * 256 + oo + 128) * 2], be1 = ab[(e * 256 + oo + 128) * 2 + 1];
  float mx0 = -__builtin_inff(), mx1 = -__builtin_inff();
  #pragma unroll
  for (int kk = 0; kk < 9; ++kk) {
    int j = knl[e ? 2 * kk : kk];
    const float* Qr = Qb + (size_t)j * 256;
    mx0 = fmaxf(mx0, fmaf(a0, p0 + Qr[oo], be0));
    mx1 = fmaxf(mx1, fmaf(a1, p1 + Qr[oo + 128], be1));
  }
  int u0 = e << 1, u1 = (e << 1) | 1;
  X16[((size_t)b * MM + 4 * n + u0) * 160 + oo] = f2bf(fmaxf(mx0, 0.f));
  X16[((size_t)b * MM + 4 * n + u1) * 160 + oo] = f2bf(fmaxf(mx1, 0.f));
  if (t < 128) {
    int u = t >> 5, c = 128 + (t & 31);
    int gr = n >> 8;
    float v = (c == 128) ? ((gr < 2) ? -0.2f : 0.2f) : (c == 129) ? ((gr & 1) ? 0.2f : -0.2f) : 0.f;
    X16[((size_t)b * MM + 4 * n + u) * 160 + c] = f2bf(v);
  }
}

// ---------------- MFMA 1x1 conv ----------------
// OUTMODE 0: f32 m-major | 1: bf16 m-major | 2: f32 ch-major
template <int KSTEPS, int CTPER, int OUTMODE, bool RELU>
__global__ __launch_bounds__(256) void k_convm(const unsigned short* __restrict__ src,
                                               const unsigned short* __restrict__ W16,
                                               const float* __restrict__ bias,
                                               float* __restrict__ dstF,
                                               unsigned short* __restrict__ dstB,
                                               int outld, int rows) {
  constexpr int LD = KSTEPS * 32;
  int t = threadIdx.x; int w = t >> 6; int l = t & 63;
  int lm = l & 15, g = l >> 4;
  int b = blockIdx.z; int ct0 = blockIdx.y * CTPER;
  int srow = blockIdx.x * 64 + w * 16 + lm;
  const unsigned short* sp = src + ((size_t)b * MM + srow) * LD + 8 * g;
  const unsigned short* wp = W16 + ((size_t)ct0 * 16 + lm) * LD + 8 * g;
  f32x4 acc[CTPER];
  #pragma unroll
  for (int i = 0; i < CTPER; ++i) acc[i] = {0.f, 0.f, 0.f, 0.f};
  #pragma unroll
  for (int cc = 0; cc < KSTEPS; ++cc) {
    short8 bfr = *(const short8*)(sp + cc * 32);
    #pragma unroll
    for (int ct = 0; ct < CTPER; ++ct) {
      short8 af = *(const short8*)(wp + (size_t)ct * 16 * LD + cc * 32);
      acc[ct] = MFMA16(af, bfr, acc[ct]);
    }
  }
  #pragma unroll
  for (int ct = 0; ct < CTPER; ++ct) {
    int o0 = (ct0 + ct) * 16 + 4 * g;
    float4 bv = *(const float4*)&bias[o0];
    float v[4] = {acc[ct][0] + bv.x, acc[ct][1] + bv.y, acc[ct][2] + bv.z, acc[ct][3] + bv.w};
    if (RELU) { v[0] = fmaxf(v[0], 0.f); v[1] = fmaxf(v[1], 0.f); v[2] = fmaxf(v[2], 0.f); v[3] = fmaxf(v[3], 0.f); }
    if (OUTMODE == 0) {
      float4 r = {v[0], v[1], v[2], v[3]};
      *(float4*)&dstF[((size_t)b * MM + srow) * outld + o0] = r;
    } else if (OUTMODE == 1) {
      uint2 pk;
      pk.x = cvtpk(v[0], v[1]);
      pk.y = cvtpk(v[2], v[3]);
      *(uint2*)&dstB[((size_t)b * MM + srow) * outld + o0] = pk;
    } else {
      #pragma unroll
      for (int r = 0; r < 4; ++r)
        dstF[((size_t)b * rows + o0 + r) * MM + srow] = v[r];
    }
  }
}

// ---------------- f/g BN stats partials over FGraw (B,MM,64) f32 ----------------
__global__ __launch_bounds__(256) void k_fgstats(const float* __restrict__ FGraw,
                                                 float* __restrict__ FGP) {
  __shared__ float red[4][64][2];
  int t = threadIdx.x; int c = t & 63, rq = t >> 6;
  int blk = blockIdx.x;
  float s = 0.f, s2 = 0.f;
  for (int k = 0; k < 64; ++k) {
    int r = blk * 256 + rq + 4 * k;
    float v = FGraw[(size_t)r * 64 + c];
    s += v; s2 += v * v;
  }
  red[rq][c][0] = s; red[rq][c][1] = s2;
  __syncthreads();
  if (t < 64) {
    float a = 0.f, a2 = 0.f;
    #pragma unroll
    for (int q = 0; q < 4; ++q) { a += red[q][t][0]; a2 += red[q][t][1]; }
    FGP[((size_t)blk * 64 + t) * 2] = a; FGP[((size_t)blk * 64 + t) * 2 + 1] = a2;
  }
}

// ---------------- H BN stats (f32 ch-major) ----------------
__global__ __launch_bounds__(256) void k_bnstats(const float* __restrict__ src,
                                                 const float* __restrict__ g,
                                                 const float* __restrict__ be,
                                                 float* __restrict__ ab, int ldC) {
  int o = blockIdx.x;
  int t = threadIdx.x;
  float s = 0.f, s2 = 0.f;
  for (int b = 0; b < NB; ++b) {
    const float* r = src + ((size_t)b * ldC + o) * MM;
    for (int m = t; m < MM; m += 256) { float v = r[m]; s += v; s2 += v * v; }
  }
  __shared__ float rs[256], rs2[256];
  rs[t] = s; rs2[t] = s2;
  __syncthreads();
  for (int off = 128; off > 0; off >>= 1) {
    if (t < off) { rs[t] += rs[t + off]; rs2[t] += rs2[t + off]; }
    __syncthreads();
  }
  if (t == 0) {
    float cnt = 16384.0f;
    float mean = rs[0] / cnt, var = rs2[0] / cnt - mean * mean;
    float alpha = g[o] * rsqrtf(var + EPSBN);
    ab[o * 2] = alpha; ab[o * 2 + 1] = be[o] - mean * alpha;
  }
}

// ---------------- cvt FGraw -> FGT bf16 (inline BN finalize + relu; F pre-scaled by LOG2E) ----------------
__global__ __launch_bounds__(256) void k_cvtFG(const float* __restrict__ FGraw,
                                               const float* __restrict__ FGP,
                                               const float* __restrict__ gf, const float* __restrict__ bef,
                                               const float* __restrict__ gg, const float* __restrict__ beg,
                                               unsigned short* __restrict__ FGT) {
  __shared__ float sab[128];
  int t = threadIdx.x;
  if (t < 64) {
    float s = 0.f, s2 = 0.f;
    for (int blk = 0; blk < 64; ++blk) {
      s += FGP[((size_t)blk * 64 + t) * 2];
      s2 += FGP[((size_t)blk * 64 + t) * 2 + 1];
    }
    float cnt = 16384.f;
    float mean = s / cnt, var = s2 / cnt - mean * mean;
    float gv = (t < 32) ? gf[t] : gg[t - 32];
    float bv = (t < 32) ? bef[t] : beg[t - 32];
    float alpha = gv * rsqrtf(var + EPSBN);
    sab[t * 2] = alpha; sab[t * 2 + 1] = bv - mean * alpha;
  }
  __syncthreads();
  int i = blockIdx.x * 256 + t;  // < 131072
  int row = i >> 3, c0 = (i & 7) * 8;
  float sc = (c0 < 32) ? LOG2E : 1.0f;
  float vv[8];
  float4 u0 = *(const float4*)&FGraw[(size_t)row * 64 + c0];
  float4 u1 = *(const float4*)&FGraw[(size_t)row * 64 + c0 + 4];
  vv[0] = u0.x; vv[1] = u0.y; vv[2] = u0.z; vv[3] = u0.w;
  vv[4] = u1.x; vv[5] = u1.y; vv[6] = u1.z; vv[7] = u1.w;
  uint4 pk;
  unsigned pw[4];
  #pragma unroll
  for (int h = 0; h < 4; ++h) {
    int c = c0 + 2 * h;
    float a0 = sab[c * 2] * sc, b0 = sab[c * 2 + 1] * sc;
    float a1 = sab[(c + 1) * 2] * sc, b1 = sab[(c + 1) * 2 + 1] * sc;
    float x0 = fmaxf(fmaf(a0, vv[2 * h], b0), 0.f);
    float x1 = fmaxf(fmaf(a1, vv[2 * h + 1], b1), 0.f);
    pw[h] = cvtpk(x0, x1);
  }
  pk.x = pw[0]; pk.y = pw[1]; pk.z = pw[2]; pk.w = pw[3];
  *(uint4*)&FGT[(size_t)row * 64 + c0] = pk;
}

// ---------------- cvt Hraw -> HB bf16 (BN+relu, ch-major, zero pad) ----------------
__global__ __launch_bounds__(256) void k_cvtH(const float* __restrict__ src,
                                              const float* __restrict__ ab,
                                              unsigned short* __restrict__ dst) {
  int i = blockIdx.x * 256 + threadIdx.x;  // (b*144 + c)*1024 + m4
  int m4 = i & 1023; int c = (i >> 10) % 144; int b = i / (144 * 1024);
  ushort4 ov = {0, 0, 0, 0};
  if (c < 130) {
    float4 v = *(const float4*)&src[((size_t)b * 144 + c) * MM + m4 * 4];
    float a = ab[c * 2], be = ab[c * 2 + 1];
    ov.x = f2bf(fmaxf(fmaf(a, v.x, be), 0.f));
    ov.y = f2bf(fmaxf(fmaf(a, v.y, be), 0.f));
    ov.z = f2bf(fmaxf(fmaf(a, v.z, be), 0.f));
    ov.w = f2bf(fmaxf(fmaf(a, v.w, be), 0.f));
  }
  *(ushort4*)&dst[((size_t)b * 144 + c) * MM + m4 * 4] = ov;
}

// ---------------- K-LSE: S in log2 domain (F pre-scaled); defer-max online ----------------
__global__ __launch_bounds__(256) void k_zlse(const unsigned short* __restrict__ FGT,
                                              float* __restrict__ LSEP) {
  int t = threadIdx.x; int w = t >> 6; int l = t & 63;
  int b = blockIdx.z; int ms = blockIdx.y;
  int n0 = blockIdx.x * 64 + w * 16;
  int lm = l & 15, g = l >> 4;
  f32x4 z4 = {0.f, 0.f, 0.f, 0.f};
  short8 af = *(const short8*)&FGT[((size_t)b * MM + n0 + lm) * 64 + 32 + 8 * g];
  float rm[4], zz[4];
  #pragma unroll
  for (int r = 0; r < 4; ++r) { rm[r] = -__builtin_inff(); zz[r] = 0.f; }
  for (int it = 0; it < 16; ++it) {
    int m0 = ms * 1024 + it * 64;
    short8 bfr[4];
    #pragma unroll
    for (int mi = 0; mi < 4; ++mi)
      bfr[mi] = *(const short8*)&FGT[((size_t)b * MM + m0 + mi * 16 + lm) * 64 + 8 * g];
    f32x4 d[4];
    #pragma unroll
    for (int mi = 0; mi < 4; ++mi) d[mi] = MFMA16(af, bfr[mi], z4);
    #pragma unroll
    for (int r = 0; r < 4; ++r) {
      float tm = fmaxf(fmaxf(d[0][r], d[1][r]), fmaxf(d[2][r], d[3][r]));
      float nm = fmaxf(rm[r], tm);
      zz[r] = zz[r] * exp2f(rm[r] - nm)
            + exp2f(d[0][r] - nm) + exp2f(d[1][r] - nm)
            + exp2f(d[2][r] - nm) + exp2f(d[3][r] - nm);
      rm[r] = nm;
    }
  }
  #pragma unroll
  for (int off = 1; off < 16; off <<= 1) {
    #pragma unroll
    for (int r = 0; r < 4; ++r) {
      float om = __shfl_xor(rm[r], off);
      float oz = __shfl_xor(zz[r], off);
      float nm = fmaxf(rm[r], om);
      zz[r] = zz[r] * exp2f(rm[r] - nm) + oz * exp2f(om - nm);
      rm[r] = nm;
    }
  }
  if (lm == 0) {
    #pragma unroll
    for (int r = 0; r < 4; ++r) {
      int n = n0 + 4 * g + r;
      size_t idx = ((size_t)ms * 16384 + (size_t)b * MM + n) * 2;
      LSEP[idx] = rm[r]; LSEP[idx + 1] = zz[r];
    }
  }
}

// ---------------- merge LSE partials ----------------
__global__ __launch_bounds__(256) void k_lsered(const float* __restrict__ LSEP,
                                                float* __restrict__ LSE) {
  int bn = blockIdx.x * 256 + threadIdx.x;  // < 16384
  float rm = -__builtin_inff(), zz = 0.f;
  #pragma unroll
  for (int ms = 0; ms < 4; ++ms) {
    float m = LSEP[((size_t)ms * 16384 + bn) * 2];
    float z = LSEP[((size_t)ms * 16384 + bn) * 2 + 1];
    float nm = fmaxf(rm, m);
    zz = zz * exp2f(rm - nm) + z * exp2f(m - nm);
    rm = nm;
  }
  LSE[bn] = rm + log2f(zz);
}

// ---------------- K-O: MFMA O-pass, LDS-staged H (reg-staged async double buffer) ----------------
// grid (32 mblocks, 4 b, 6 splits), 256 thr (4 waves). H chunk (144ch x 32n bf16)
// staged once per block into LDS (rows padded 64->80B), shared by all 4 waves.
__global__ __launch_bounds__(256) void k_omfma(const unsigned short* __restrict__ FGT,
                                               const unsigned short* __restrict__ HB,
                                               const float* __restrict__ LSE,
                                               unsigned short* __restrict__ Opart) {
  __shared__ __align__(16) unsigned short Hs[2][144 * 40];  // 2 x 11520 B
  int t = threadIdx.x; int w = t >> 6; int l = t & 63;
  int b = blockIdx.y; int split = blockIdx.z;
  int lm = l & 15, g = l >> 4;
  int mcol0 = blockIdx.x * 128 + w * 32 + lm;
  int mcol1 = mcol0 + 16;
  f32x4 z4 = {0.f, 0.f, 0.f, 0.f};
  short8 Ff0 = *(const short8*)&FGT[((size_t)b * MM + mcol0) * 64 + 8 * g];
  short8 Ff1 = *(const short8*)&FGT[((size_t)b * MM + mcol1) * 64 + 8 * g];
  f32x4 acc0[9], acc1[9];
  #pragma unroll
  for (int ct = 0; ct < 9; ++ct) { acc0[ct] = z4; acc1[ct] = z4; }
  const int nchunks = (split < 2) ? 22 : 21;
  const int startc = split * 21 + ((split < 2) ? split : 2);
  const int start = startc * 32;
  const unsigned short* gptr = FGT + ((size_t)b * MM + lm) * 64 + 32 + 8 * g;
  const unsigned short* hsrc = HB + (size_t)b * 144 * MM;
  const float* lbase = LSE + (size_t)b * MM + 4 * g;
  int src01 = lm + 16 * (2 * (g & 1));
  int src23 = src01 + 16;
  bool hi = g >= 2;
  // staging indices for this thread (3 slots, 576 total items)
  int sidx0 = t, sidx1 = t + 256, sidx2 = t + 512;
  int ch0 = sidx0 >> 2, sg0 = sidx0 & 3;
  int ch1 = sidx1 >> 2, sg1 = sidx1 & 3;
  int ch2 = (sidx2 < 576) ? (sidx2 >> 2) : 0;
  int sg2 = sidx2 & 3;
  bool has2 = sidx2 < 576;

  // preamble: stage chunk 0 into buf 0
  {
    uint4 r0 = *(const uint4*)(hsrc + (size_t)ch0 * MM + start + sg0 * 8);
    uint4 r1 = *(const uint4*)(hsrc + (size_t)ch1 * MM + start + sg1 * 8);
    uint4 r2 = has2 ? *(const uint4*)(hsrc + (size_t)ch2 * MM + start + sg2 * 8) : uint4{0,0,0,0};
    *(uint4*)&Hs[0][ch0 * 40 + sg0 * 8] = r0;
    *(uint4*)&Hs[0][ch1 * 40 + sg1 * 8] = r1;
    if (has2) *(uint4*)&Hs[0][ch2 * 40 + sg2 * 8] = r2;
  }
  // G/LSE for chunk 0
  short8 a0 = *(const short8*)(gptr + (size_t)start * 64);
  short8 a1 = *(const short8*)(gptr + (size_t)(start + 16) * 64);
  float4 l0 = *(const float4*)(lbase + start);
  float4 l1 = *(const float4*)(lbase + start + 16);
  __syncthreads();

  for (int it = 0; it < nchunks; ++it) {
    int n0 = start + it * 32;
    int cur = it & 1;
    bool more = (it + 1 < nchunks);
    int n1 = more ? (n0 + 32) : start;
    // (A) issue global loads for NEXT H chunk into regs (latency hides under compute)
    uint4 r0, r1, r2;
    if (more) {
      r0 = *(const uint4*)(hsrc + (size_t)ch0 * MM + n1 + sg0 * 8);
      r1 = *(const uint4*)(hsrc + (size_t)ch1 * MM + n1 + sg1 * 8);
      if (has2) r2 = *(const uint4*)(hsrc + (size_t)ch2 * MM + n1 + sg2 * 8);
    }
    // next G/LSE into regs
    short8 na0 = *(const short8*)(gptr + (size_t)n1 * 64);
    short8 na1 = *(const short8*)(gptr + (size_t)(n1 + 16) * 64);
    float4 nl0 = *(const float4*)(lbase + n1);
    float4 nl1 = *(const float4*)(lbase + n1 + 16);
    // (B) compute current chunk from LDS buf[cur]
    short8 hf[9];
    #pragma unroll
    for (int ct = 0; ct < 9; ++ct)
      hf[ct] = *(const short8*)&Hs[cur][(lm + 16 * ct) * 40 + g * 8];
    f32x4 s00 = MFMA16(a0, Ff0, z4);
    f32x4 s10 = MFMA16(a1, Ff0, z4);
    f32x4 s01 = MFMA16(a0, Ff1, z4);
    f32x4 s11 = MFMA16(a1, Ff1, z4);
    float le0[4] = {l0.x, l0.y, l0.z, l0.w};
    float le1[4] = {l1.x, l1.y, l1.z, l1.w};
    unsigned pk00[2], pk10[2], pk01[2], pk11[2];
    #pragma unroll
    for (int h2 = 0; h2 < 2; ++h2) {
      pk00[h2] = cvtpk(exp2f(s00[2*h2] - le0[2*h2]), exp2f(s00[2*h2+1] - le0[2*h2+1]));
      pk10[h2] = cvtpk(exp2f(s10[2*h2] - le1[2*h2]), exp2f(s10[2*h2+1] - le1[2*h2+1]));
      pk01[h2] = cvtpk(exp2f(s01[2*h2] - le0[2*h2]), exp2f(s01[2*h2+1] - le0[2*h2+1]));
      pk11[h2] = cvtpk(exp2f(s11[2*h2] - le1[2*h2]), exp2f(s11[2*h2+1] - le1[2*h2+1]));
    }
    unsigned a0w = (unsigned)__shfl((int)pk00[0], src01);
    unsigned b0w = (unsigned)__shfl((int)pk10[0], src01);
    unsigned a1w = (unsigned)__shfl((int)pk00[1], src01);
    unsigned b1w = (unsigned)__shfl((int)pk10[1], src01);
    unsigned a2w = (unsigned)__shfl((int)pk00[0], src23);
    unsigned b2w = (unsigned)__shfl((int)pk10[0], src23);
    unsigned a3w = (unsigned)__shfl((int)pk00[1], src23);
    unsigned b3w = (unsigned)__shfl((int)pk10[1], src23);
    union { unsigned u[4]; short8 s; } bu0;
    bu0.u[0] = hi ? b0w : a0w; bu0.u[1] = hi ? b1w : a1w;
    bu0.u[2] = hi ? b2w : a2w; bu0.u[3] = hi ? b3w : a3w;
    short8 bfrag0 = bu0.s;
    unsigned c0w = (unsigned)__shfl((int)pk01[0], src01);
    unsigned d0w = (unsigned)__shfl((int)pk11[0], src01);
    unsigned c1w = (unsigned)__shfl((int)pk01[1], src01);
    unsigned d1w = (unsigned)__shfl((int)pk11[1], src01);
    unsigned c2w = (unsigned)__shfl((int)pk01[0], src23);
    unsigned d2w = (unsigned)__shfl((int)pk11[0], src23);
    unsigned c3w = (unsigned)__shfl((int)pk01[1], src23);
    unsigned d3w = (unsigned)__shfl((int)pk11[1], src23);
    union { unsigned u[4]; short8 s; } bu1;
    bu1.u[0] = hi ? d0w : c0w; bu1.u[1] = hi ? d1w : c1w;
    bu1.u[2] = hi ? d2w : c2w; bu1.u[3] = hi ? d3w : c3w;
    short8 bfrag1 = bu1.s;
    __builtin_amdgcn_s_setprio(1);
    #pragma unroll
    for (int ct = 0; ct < 9; ++ct) {
      acc0[ct] = MFMA16(hf[ct], bfrag0, acc0[ct]);
      acc1[ct] = MFMA16(hf[ct], bfrag1, acc1[ct]);
    }
    __builtin_amdgcn_s_setprio(0);
    // (C) write staged regs into the other buffer, (D) barrier
    if (more) {
      *(uint4*)&Hs[cur ^ 1][ch0 * 40 + sg0 * 8] = r0;
      *(uint4*)&Hs[cur ^ 1][ch1 * 40 + sg1 * 8] = r1;
      if (has2) *(uint4*)&Hs[cur ^ 1][ch2 * 40 + sg2 * 8] = r2;
    }
    a0 = na0; a1 = na1; l0 = nl0; l1 = nl1;
    __syncthreads();
  }

  unsigned short* op0 = Opart + (size_t)split * OPS_SH + ((size_t)b * MM + mcol0) * 132;
  unsigned short* op1 = Opart + (size_t)split * OPS_SH + ((size_t)b * MM + mcol1) * 132;
  #pragma unroll
  for (int ct = 0; ct < 9; ++ct) {
    int c0 = ct * 16 + 4 * g;
    if (c0 < 132) {
      uint2 p0, p1;
      p0.x = cvtpk(acc0[ct][0], acc0[ct][1]);
      p0.y = cvtpk(acc0[ct][2], acc0[ct][3]);
      p1.x = cvtpk(acc1[ct][0], acc1[ct][1]);
      p1.y = cvtpk(acc1[ct][2], acc1[ct][3]);
      *(uint2*)&op0[c0] = p0;
      *(uint2*)&op1[c0] = p1;
    }
  }
}

// ---------------- O reduce: A16 = bf16(gamma*sum(Oparts) + X) ----------------
__global__ __launch_bounds__(256) void k_ored(const unsigned short* __restrict__ Op,
                                              const unsigned short* __restrict__ X16,
                                              const float* __restrict__ gma,
                                              unsigned short* __restrict__ A16) {
  int i = blockIdx.x * 256 + threadIdx.x;  // < 327680
  int row = i / 20, c8 = i % 20;
  int c0 = c8 * 8;
  unsigned short* ap = A16 + (size_t)row * 160 + c0;
  if (c0 >= 136) {
    uint4 z = {0, 0, 0, 0};
    *(uint4*)ap = z;
    return;
  }
  float gm = gma[0];
  float ov[8] = {0.f, 0.f, 0.f, 0.f, 0.f, 0.f, 0.f, 0.f};
  #pragma unroll
  for (int s = 0; s < 6; ++s) {
    const unsigned short* base = Op + (size_t)s * OPS_SH + (size_t)row * 132 + c0;
    uint2 u = *(const uint2*)base;
    ov[0] += bf2f((unsigned short)(u.x & 0xffff));
    ov[1] += bf2f((unsigned short)(u.x >> 16));
    ov[2] += bf2f((unsigned short)(u.y & 0xffff));
    ov[3] += bf2f((unsigned short)(u.y >> 16));
    if (c0 + 4 < 132) {
      uint2 v = *(const uint2*)(base + 4);
      ov[4] += bf2f((unsigned short)(v.x & 0xffff));
      ov[5] += bf2f((unsigned short)(v.x >> 16));
      ov[6] += bf2f((unsigned short)(v.y & 0xffff));
      ov[7] += bf2f((unsigned short)(v.y >> 16));
    }
  }
  short8 xv = *(const short8*)(X16 + (size_t)row * 160 + c0);
  unsigned pw[4];
  #pragma unroll
  for (int h = 0; h < 4; ++h) {
    int ca = c0 + 2 * h, cb = c0 + 2 * h + 1;
    float xa = bf2f((unsigned short)xv[2 * h]);
    float xb = bf2f((unsigned short)xv[2 * h + 1]);
    float va = (ca < 132) ? (gm * ov[2 * h] + xa) : 0.f;
    float vb = (cb < 132) ? (gm * ov[2 * h + 1] + xb) : 0.f;
    pw[h] = (unsigned)f2bf(va) | ((unsigned)f2bf(vb) << 16);
  }
  uint4 pk = {pw[0], pw[1], pw[2], pw[3]};
  *(uint4*)ap = pk;
}

extern "C" void kernel_launch(void* const* d_in, const int* in_sizes, int n_in,
                              void* d_out, int out_size, void* d_ws, size_t ws_size,
                              hipStream_t stream) {
  const float* inp = (const float*)d_in[0];
  const float* Wa  = (const float*)d_in[1];
  const float* gna = (const float*)d_in[2];
  const float* bta = (const float*)d_in[3];
  const float* Wb  = (const float*)d_in[4];
  const float* gnb = (const float*)d_in[5];
  const float* btb = (const float*)d_in[6];
  const float* Wf  = (const float*)d_in[7];
  const float* bf  = (const float*)d_in[8];
  const float* gf  = (const float*)d_in[9];
  const float* bef = (const float*)d_in[10];
  const float* Wg  = (const float*)d_in[11];
  const float* bg  = (const float*)d_in[12];
  const float* gg  = (const float*)d_in[13];
  const float* beg = (const float*)d_in[14];
  const float* Wh  = (const float*)d_in[15];
  const float* bh  = (const float*)d_in[16];
  const float* gh  = (const float*)d_in[17];
  const float* beh = (const float*)d_in[18];
  const float* gamma = (const float*)d_in[19];
  const float* W1  = (const float*)d_in[20];
  const float* b1  = (const float*)d_in[21];
  const float* W2  = (const float*)d_in[22];
  const float* b2  = (const float*)d_in[23];
  float* out = (float*)d_out;

  float* ws = (float*)d_ws;
  float* DIST = ws + OFF_DIST;
  float* PM   = ws + OFF_PM;
  float* QM   = ws + OFF_QM;
  float* HRAW = ws + OFF_HRAW;
  float* FGRAW= ws + OFF_FGRAW;
  unsigned short* OP16 = (unsigned short*)(ws + OFF_OP);
  unsigned short* FGT = (unsigned short*)(ws + OFF_FGT);
  unsigned short* HBB = (unsigned short*)(ws + OFF_HB);
  unsigned short* A16 = (unsigned short*)(ws + OFF_A16);
  unsigned short* X16 = (unsigned short*)(ws + OFF_X16);
  unsigned short* Y1  = (unsigned short*)(ws + OFF_Y1);
  float* LSEB = ws + OFF_LSE;
  float* LSEP = ws + OFF_LSEP;
  float* STATS= ws + OFF_STATS;
  float* ABE  = ws + OFF_ABE;
  float* ABH  = ws + OFF_ABH;
  float* FGP  = ws + OFF_FGP;
  float* BIAS = ws + OFF_BIAS;
  unsigned short* W16 = (unsigned short*)(ws + OFF_W16);
  int*   KNNI = (int*)(ws + OFF_KNN);
  float* XN   = ws + OFF_XN;
  unsigned short* XR = (unsigned short*)(ws + OFF_XR);
  unsigned short* WPQ = (unsigned short*)(ws + OFF_WPQ);
  float* SQ   = ws + OFF_SQ;

  // 0. fused prep + normalize
  k_init<<<949, 256, 0, stream>>>(Wf, Wg, Wh, W1, W2, bf, bg, bh, b1, b2, Wa, Wb, W16, BIAS, WPQ,
                                  inp, XN, XR, SQ);
  // 1-2. fp32 dist 128x64 (exact kNN path), knn
  k_dist<<<dim3(16, 8, 4), 256, 0, stream>>>(XN, SQ, DIST);
  k_knn<<<4096, 64, 0, stream>>>(DIST, KNNI);
  // 3. P/Q MFMA (overwrites DIST) ; 4-5. edge BN ; 6. apply -> X16
  k_pqm<<<dim3(16, 4, 8), 256, 0, stream>>>(XR, WPQ, PM, QM);
  k_edge_stats<<<dim3(16, 4, 2), 256, 0, stream>>>(PM, QM, KNNI, STATS);
  k_edge_fin<<<2, 256, 0, stream>>>(STATS, gna, bta, gnb, btb, ABE);
  k_edge_apply<<<dim3(1024, 4), 256, 0, stream>>>(PM, QM, KNNI, ABE, X16);
  // 7. f+g conv (f32 m-major raw) and h conv (f32 ch-major raw), over dead PM/QM region
  k_convm<5, 2, 0, false><<<dim3(64, 2, 4), 256, 0, stream>>>(X16, W16 + W16_FG, BIAS + B_FG, FGRAW, nullptr, 64, 0);
  k_convm<5, 3, 2, false><<<dim3(64, 3, 4), 256, 0, stream>>>(X16, W16 + W16_H, BIAS + B_H, HRAW, nullptr, 0, 144);
  // 8. BN stats + fused apply/cvt to bf16 (fg finalize inlined in cvtFG)
  k_fgstats<<<64, 256, 0, stream>>>(FGRAW, FGP);
  k_bnstats<<<130, 256, 0, stream>>>(HRAW, gh, beh, ABH, 144);
  k_cvtFG<<<512, 256, 0, stream>>>(FGRAW, FGP, gf, bef, gg, beg, FGT);
  k_cvtH<<<2304, 256, 0, stream>>>(HRAW, ABH, HBB);
  // 9. LSE ; 10. O-pass (LDS-staged H double buffer) ; 11. reduce -> A16
  k_zlse<<<dim3(64, 4, 4), 256, 0, stream>>>(FGT, LSEP);
  k_lsered<<<64, 256, 0, stream>>>(LSEP, LSEB);
  k_omfma<<<dim3(32, 4, 6), 256, 0, stream>>>(FGT, HBB, LSEB, OP16);
  k_ored<<<1280, 256, 0, stream>>>(OP16, X16, gamma, A16);
  // 12-13. final convs (MFMA)
  k_convm<5, 8, 1, true><<<dim3(64, 2, 4), 256, 0, stream>>>(A16, W16 + W16_C1, BIAS + B_C1, nullptr, Y1, 256, 0);
  k_convm<8, 4, 2, true><<<dim3(64, 2, 4), 256, 0, stream>>>(Y1, W16 + W16_C2, BIAS + B_C2, out, nullptr, 0, 128);
}

// Round 14
// 306.904 us; speedup vs baseline: 1.0340x; 1.0205x over previous
//
#include <hip/hip_runtime.h>

namespace {
constexpr int NB = 4;      // batch
constexpr int CI = 128;    // input channels
constexpr int NP = 1024;   // points
constexpr int MM = 4096;   // N*UP
constexpr float EPSBN = 1e-5f;
constexpr float LOG2E = 1.4426950408889634f;

constexpr size_t OPS_SH = 2162688;       // Opart split stride in SHORTS (B*MM*132)
// workspace offsets (floats)
constexpr size_t OFF_OP   = 0;           // 6 bf16 splits = 6488064 floats (overlaid: DIST / Pm,Qm / Hraw,FGraw / Y1)
constexpr size_t OFF_DIST = 0;           // 4194304
constexpr size_t OFF_PM   = 0;           // 2097152
constexpr size_t OFF_QM   = 2097152;     // 2097152
constexpr size_t OFF_HRAW = 0;           // 2359296 (B,144,MM) f32
constexpr size_t OFF_FGRAW= 2359296;     // 1048576 (B,MM,64) f32  -> ends 3407872
constexpr size_t OFF_Y1   = 0;           // (B,MM,256) bf16 = 2097152 floats
constexpr size_t OFF_FGT  = 6488064;     // (B,MM,64) bf16 = 524288 floats
constexpr size_t OFF_HB   = 7012352;     // (B,144,MM) bf16 = 1179648 floats
constexpr size_t OFF_A16  = 6488064;     // (B,MM,160) bf16 = 1310720 floats (over FGT/HB after omfma)
constexpr size_t OFF_X16  = 8192000;     // (B,MM,160) bf16 = 1310720 floats
constexpr size_t OFF_LSE  = 9502720;     // 16384
constexpr size_t OFF_LSEP = 9519104;     // 131072
constexpr size_t OFF_STATS= 9650176;     // 65536
constexpr size_t OFF_ABE  = 9715712;     // 1024
constexpr size_t OFF_ABH  = 9716864;     // 512
constexpr size_t OFF_FGP  = 9717376;     // 8192
constexpr size_t OFF_BIAS = 9725568;     // 640
constexpr size_t OFF_W16  = 9726208;     // 53504 (107008 shorts)
constexpr size_t OFF_KNN  = 9779712;     // 73728 ints
constexpr size_t OFF_XN   = 9853440;     // (B,128,1024) f32 = 524288 (normalized, ch-major, for fp32 dist)
constexpr size_t OFF_SQ   = 10377728;    // 4096
constexpr size_t OFF_XR   = 10381824;    // (B,1024,128) bf16 raw = 262144 floats
constexpr size_t OFF_WPQ  = 10643968;    // 65536 floats (131072 shorts) -> ends 10709504
// W16 sub-offsets (shorts)
constexpr size_t W16_FG = 0;       // 64x160
constexpr size_t W16_H  = 10240;   // 144x160
constexpr size_t W16_C1 = 33280;   // 256x160
constexpr size_t W16_C2 = 74240;   // 128x256
// BIAS sub-offsets (floats)
constexpr size_t B_FG = 0, B_H = 64, B_C1 = 208, B_C2 = 464;
} // namespace

typedef __attribute__((ext_vector_type(8))) short short8;
typedef __attribute__((ext_vector_type(4))) float f32x4;
#define MFMA16(A, B, C) __builtin_amdgcn_mfma_f32_16x16x32_bf16(A, B, C, 0, 0, 0)

__device__ inline unsigned short f2bf(float x) {
  unsigned int u = __float_as_uint(x);
  unsigned int r = u + 0x7fff + ((u >> 16) & 1);
  return (unsigned short)(r >> 16);
}
__device__ inline float bf2f(unsigned short s) {
  return __uint_as_float(((unsigned int)s) << 16);
}
__device__ inline unsigned cvtpk(float lo, float hi) {
  unsigned r;
  asm("v_cvt_pk_bf16_f32 %0, %1, %2" : "=v"(r) : "v"(lo), "v"(hi));
  return r;
}

// ---------------- K0: fused weight-prep + normalize ----------------
__global__ __launch_bounds__(256) void k_init(const float* __restrict__ Wf, const float* __restrict__ Wg,
                                              const float* __restrict__ Wh, const float* __restrict__ W1,
                                              const float* __restrict__ W2, const float* __restrict__ bf,
                                              const float* __restrict__ bg, const float* __restrict__ bh,
                                              const float* __restrict__ b1, const float* __restrict__ b2,
                                              const float* __restrict__ Wa, const float* __restrict__ Wb,
                                              unsigned short* __restrict__ W16, float* __restrict__ BIAS,
                                              unsigned short* __restrict__ WPQ,
                                              const float* __restrict__ x,
                                              float* __restrict__ xn,
                                              unsigned short* __restrict__ XR,
                                              float* __restrict__ sq) {
  if (blockIdx.x < 933) {
    int i = blockIdx.x * 256 + threadIdx.x;
    if (i < 107008) {
      float v = 0.f;
      if (i < 10240) { int o = i / 160, c = i % 160; if (c < 130) v = (o < 32) ? Wf[o * 130 + c] : Wg[(o - 32) * 130 + c]; }
      else if (i < 33280) { int r = i - 10240; int o = r / 160, c = r % 160; if (o < 130 && c < 130) v = Wh[o * 130 + c]; }
      else if (i < 74240) { int r = i - 33280; int o = r / 160, c = r % 160; if (c < 130) v = W1[o * 130 + c]; }
      else { int r = i - 74240; int o = r / 256, c = r % 256; v = W2[o * 256 + c]; }
      W16[i] = f2bf(v);
    } else if (i < 107648) {
      int j = i - 107008; float v = 0.f;
      if (j < 64) v = (j < 32) ? bf[j] : bg[j - 32];
      else if (j < 208) { int c = j - 64; if (c < 130) v = bh[c]; }
      else if (j < 464) v = b1[j - 208];
      else if (j < 592) v = b2[j - 464];
      BIAS[j] = v;
    } else if (i < 238720) {
      int j = i - 107648;
      int e = j >> 16;
      int rem = j & 65535;
      int pq = rem >> 15;
      int rr = rem & 32767;
      int o = rr >> 7, c = rr & 127;
      const float* W = e ? Wb : Wa;
      float w1 = W[o * 256 + c], w2 = W[o * 256 + 128 + c];
      float v = pq ? w2 : (w1 - w2);
      WPQ[j] = f2bf(v);
    }
  } else {
    int t = (blockIdx.x - 933) * 256 + threadIdx.x;   // b*1024+n
    int b = t >> 10, n = t & 1023;
    const float* xb = x + (size_t)b * CI * NP + n;
    float ss = 0.f;
    #pragma unroll 4
    for (int c = 0; c < CI; ++c) { float v = xb[(size_t)c * NP]; ss += v * v; }
    float inv = 1.f / fmaxf(sqrtf(ss), 1e-12f);
    float* xo = xn + (size_t)b * CI * NP + n;
    float s2 = 0.f;
    for (int c0 = 0; c0 < 128; c0 += 8) {
      unsigned rw[4];
      #pragma unroll
      for (int j = 0; j < 4; ++j) {
        float va = xb[(size_t)(c0 + 2 * j) * NP];
        float vb = xb[(size_t)(c0 + 2 * j + 1) * NP];
        float na = va * inv, nb = vb * inv;
        s2 += na * na + nb * nb;
        xo[(size_t)(c0 + 2 * j) * NP] = na;
        xo[(size_t)(c0 + 2 * j + 1) * NP] = nb;
        rw[j] = (unsigned)f2bf(va) | ((unsigned)f2bf(vb) << 16);
      }
      uint4 r4 = {rw[0], rw[1], rw[2], rw[3]};
      *(uint4*)&XR[(size_t)t * 128 + c0] = r4;
    }
    sq[t] = s2;
  }
}

// ---------------- K2: pairwise distance, fp32 128x64 tile (exact kNN path; same fp order) ----------------
__global__ __launch_bounds__(256) void k_dist(const float* __restrict__ xn,
                                              const float* __restrict__ sq,
                                              float* __restrict__ dist) {
  __shared__ float As[32][132], Bs[32][68];
  int t = threadIdx.x;
  int m0 = blockIdx.x * 64, n0 = blockIdx.y * 128, b = blockIdx.z;
  int mg = t & 15, ng = t >> 4;
  float acc[8][4];
  #pragma unroll
  for (int i = 0; i < 8; ++i)
    #pragma unroll
    for (int j = 0; j < 4; ++j) acc[i][j] = 0.f;
  for (int cc = 0; cc < 128; cc += 32) {
    __syncthreads();
    for (int idx = t; idx < 4096; idx += 256) {
      int c = idx >> 7, j = idx & 127;
      As[c][j] = xn[((size_t)b * CI + cc + c) * NP + n0 + j];
    }
    for (int idx = t; idx < 2048; idx += 256) {
      int c = idx >> 6, j = idx & 63;
      Bs[c][j] = xn[((size_t)b * CI + cc + c) * NP + m0 + j];
    }
    __syncthreads();
    #pragma unroll
    for (int c = 0; c < 32; ++c) {
      float4 a0 = *(const float4*)&As[c][ng * 8];
      float4 a1 = *(const float4*)&As[c][ng * 8 + 4];
      float4 b0 = *(const float4*)&Bs[c][mg * 4];
      float av[8] = {a0.x, a0.y, a0.z, a0.w, a1.x, a1.y, a1.z, a1.w};
      float bv[4] = {b0.x, b0.y, b0.z, b0.w};
      #pragma unroll
      for (int i = 0; i < 8; ++i)
        #pragma unroll
        for (int j = 0; j < 4; ++j) acc[i][j] += av[i] * bv[j];
    }
  }
  #pragma unroll
  for (int i = 0; i < 8; ++i) {
    int n = n0 + ng * 8 + i;
    float sn = sq[b * NP + n];
    int mb = m0 + mg * 4;
    float4 r;
    r.x = sn + sq[b * NP + mb + 0] - 2.f * acc[i][0];
    r.y = sn + sq[b * NP + mb + 1] - 2.f * acc[i][1];
    r.z = sn + sq[b * NP + mb + 2] - 2.f * acc[i][2];
    r.w = sn + sq[b * NP + mb + 3] - 2.f * acc[i][3];
    *(float4*)&dist[((size_t)b * NP + n) * NP + mb] = r;
  }
}

// ---------------- K3: top-18 nearest per row ----------------
__global__ __launch_bounds__(64) void k_knn(const float* __restrict__ dist,
                                            int* __restrict__ knn) {
  int row = blockIdx.x;
  int l = threadIdx.x;
  const float* dr = dist + (size_t)row * NP;
  float d[16];
  #pragma unroll
  for (int i = 0; i < 16; ++i) d[i] = dr[l + 64 * i];
  for (int s = 0; s < 18; ++s) {
    float best = __builtin_inff(); int bslot = -1;
    #pragma unroll
    for (int i = 0; i < 16; ++i) if (d[i] < best) { best = d[i]; bslot = i; }
    int bidx = (bslot >= 0) ? (l + 64 * bslot) : 0x7fffffff;
    float bd = best; int bi = bidx;
    #pragma unroll
    for (int off = 32; off > 0; off >>= 1) {
      float od = __shfl_xor(bd, off);
      int   oi = __shfl_xor(bi, off);
      if (od < bd || (od == bd && oi < bi)) { bd = od; bi = oi; }
    }
    if (l == 0) knn[row * 18 + s] = bi;
    if ((bi & 63) == l) d[bi >> 6] = __builtin_inff();
  }
}

// ---------------- K4: P/Q pre-GEMMs via MFMA, m-major f32 out ----------------
__global__ __launch_bounds__(256) void k_pqm(const unsigned short* __restrict__ XR,
                                             const unsigned short* __restrict__ WPQ,
                                             float* __restrict__ Pm,
                                             float* __restrict__ Qm) {
  int t = threadIdx.x; int w = t >> 6; int l = t & 63;
  int lm = l & 15, g = l >> 4;
  int nt = blockIdx.x, oq = blockIdx.y, z = blockIdx.z;
  int e = z >> 2, b = z & 3;
  int srow = nt * 64 + w * 16 + lm;
  const unsigned short* sp = XR + ((size_t)b * 1024 + srow) * 128 + 8 * g;
  const unsigned short* wpp = WPQ + ((size_t)(e * 2 + 0) * 256 + oq * 64 + lm) * 128 + 8 * g;
  const unsigned short* wqq = WPQ + ((size_t)(e * 2 + 1) * 256 + oq * 64 + lm) * 128 + 8 * g;
  f32x4 accp[4], accq[4];
  #pragma unroll
  for (int i = 0; i < 4; ++i) { accp[i] = {0.f, 0.f, 0.f, 0.f}; accq[i] = {0.f, 0.f, 0.f, 0.f}; }
  #pragma unroll
  for (int cc = 0; cc < 4; ++cc) {
    short8 bfr = *(const short8*)(sp + cc * 32);
    #pragma unroll
    for (int ct = 0; ct < 4; ++ct) {
      short8 ap = *(const short8*)(wpp + (size_t)ct * 16 * 128 + cc * 32);
      accp[ct] = MFMA16(ap, bfr, accp[ct]);
      short8 aq = *(const short8*)(wqq + (size_t)ct * 16 * 128 + cc * 32);
      accq[ct] = MFMA16(aq, bfr, accq[ct]);
    }
  }
  int eb = e * 4 + b;
  #pragma unroll
  for (int ct = 0; ct < 4; ++ct) {
    int o0 = oq * 64 + ct * 16 + 4 * g;
    float4 rp = {accp[ct][0], accp[ct][1], accp[ct][2], accp[ct][3]};
    float4 rq = {accq[ct][0], accq[ct][1], accq[ct][2], accq[ct][3]};
    *(float4*)&Pm[((size_t)eb * 1024 + srow) * 256 + o0] = rp;
    *(float4*)&Qm[((size_t)eb * 1024 + srow) * 256 + o0] = rq;
  }
}

// ---------------- K5: edge BN stats partials ----------------
__global__ __launch_bounds__(256) void k_edge_stats(const float* __restrict__ Pm,
                                                    const float* __restrict__ Qm,
                                                    const int* __restrict__ knn,
                                                    float* __restrict__ stats) {
  int o = threadIdx.x;
  int chunk = blockIdx.x, b = blockIdx.y, e = blockIdx.z;
  int eb = e * 4 + b;
  float s = 0.f, s2 = 0.f;
  for (int nn = 0; nn < 64; ++nn) {
    int n = chunk * 64 + nn;
    float p = Pm[((size_t)eb * 1024 + n) * 256 + o];
    const int* kn = knn + (b * 1024 + n) * 18;
    #pragma unroll
    for (int kk = 0; kk < 9; ++kk) {
      int j = kn[e ? 2 * kk : kk];
      float v = p + Qm[((size_t)eb * 1024 + j) * 256 + o];
      s += v; s2 += v * v;
    }
  }
  size_t idx = ((((size_t)e * 4 + b) * 16 + chunk) * 256 + o) * 2;
  stats[idx] = s; stats[idx + 1] = s2;
}

// ---------------- K6: finalize edge BN ----------------
__global__ __launch_bounds__(256) void k_edge_fin(const float* __restrict__ stats,
                                                  const float* __restrict__ gna, const float* __restrict__ bta,
                                                  const float* __restrict__ gnb, const float* __restrict__ btb,
                                                  float* __restrict__ ab) {
  int i = blockIdx.x * 256 + threadIdx.x;
  if (i >= 512) return;
  int e = i >> 8, o = i & 255;
  float s = 0.f, s2 = 0.f;
  for (int b = 0; b < 4; ++b)
    for (int ch = 0; ch < 16; ++ch) {
      size_t idx = ((((size_t)e * 4 + b) * 16 + ch) * 256 + o) * 2;
      s += stats[idx]; s2 += stats[idx + 1];
    }
  float cnt = 4.0f * 1024.0f * 9.0f;
  float mean = s / cnt;
  float var = s2 / cnt - mean * mean;
  float g = e ? gnb[o] : gna[o];
  float bt = e ? btb[o] : bta[o];
  float alpha = g * rsqrtf(var + EPSBN);
  ab[i * 2] = alpha; ab[i * 2 + 1] = bt - mean * alpha;
}

// ---------------- K7: edge apply + max-over-k -> X16 (B,MM,160) bf16 ----------------
__global__ __launch_bounds__(256) void k_edge_apply(const float* __restrict__ Pm,
                                                    const float* __restrict__ Qm,
                                                    const int* __restrict__ knn,
                                                    const float* __restrict__ ab,
                                                    unsigned short* __restrict__ X16) {
  __shared__ int knl[18];
  int t = threadIdx.x;
  int n = blockIdx.x, b = blockIdx.y;
  if (t < 18) knl[t] = knn[(b * 1024 + n) * 18 + t];
  __syncthreads();
  int e = t >> 7, oo = t & 127;
  int eb = e * 4 + b;
  const float* Pr = Pm + ((size_t)eb * 1024 + n) * 256;
  const float* Qb = Qm + (size_t)eb * 1024 * 256;
  float p0 = Pr[oo], p1 = Pr[oo + 128];
  float a0 = ab[(e * 256 + oo) * 2], be0 = ab[(e * 256 + oo) * 2 + 1];
  float a1 = ab[(e * 256 + oo + 128) * 2], be1 = ab[(e * 256 + oo + 128) * 2 + 1];
  float mx0 = -__builtin_inff(), mx1 = -__builtin_inff();
  #pragma unroll
  for (int kk = 0; kk < 9; ++kk) {
    int j = knl[e ? 2 * kk : kk];
    const float* Qr = Qb + (size_t)j * 256;
    mx0 = fmaxf(mx0, fmaf(a0, p0 + Qr[oo], be0));
    mx1 = fmaxf(mx1, fmaf(a1, p1 + Qr[oo + 128], be1));
  }
  int u0 = e << 1, u1 = (e << 1) | 1;
  X16[((size_t)b * MM + 4 * n + u0) * 160 + oo] = f2bf(fmaxf(mx0, 0.f));
  X16[((size_t)b * MM + 4 * n + u1) * 160 + oo] = f2bf(fmaxf(mx1, 0.f));
  if (t < 128) {
    int u = t >> 5, c = 128 + (t & 31);
    int gr = n >> 8;
    float v = (c == 128) ? ((gr < 2) ? -0.2f : 0.2f) : (c == 129) ? ((gr & 1) ? 0.2f : -0.2f) : 0.f;
    X16[((size_t)b * MM + 4 * n + u) * 160 + c] = f2bf(v);
  }
}

// ---------------- MFMA 1x1 conv ----------------
// OUTMODE 0: f32 m-major | 1: bf16 m-major | 2: f32 ch-major
template <int KSTEPS, int CTPER, int OUTMODE, bool RELU>
__global__ __launch_bounds__(256) void k_convm(const unsigned short* __restrict__ src,
                                               const unsigned short* __restrict__ W16,
                                               const float* __restrict__ bias,
                                               float* __restrict__ dstF,
                                               unsigned short* __restrict__ dstB,
                                               int outld, int rows) {
  constexpr int LD = KSTEPS * 32;
  int t = threadIdx.x; int w = t >> 6; int l = t & 63;
  int lm = l & 15, g = l >> 4;
  int b = blockIdx.z; int ct0 = blockIdx.y * CTPER;
  int srow = blockIdx.x * 64 + w * 16 + lm;
  const unsigned short* sp = src + ((size_t)b * MM + srow) * LD + 8 * g;
  const unsigned short* wp = W16 + ((size_t)ct0 * 16 + lm) * LD + 8 * g;
  f32x4 acc[CTPER];
  #pragma unroll
  for (int i = 0; i < CTPER; ++i) acc[i] = {0.f, 0.f, 0.f, 0.f};
  #pragma unroll
  for (int cc = 0; cc < KSTEPS; ++cc) {
    short8 bfr = *(const short8*)(sp + cc * 32);
    #pragma unroll
    for (int ct = 0; ct < CTPER; ++ct) {
      short8 af = *(const short8*)(wp + (size_t)ct * 16 * LD + cc * 32);
      acc[ct] = MFMA16(af, bfr, acc[ct]);
    }
  }
  #pragma unroll
  for (int ct = 0; ct < CTPER; ++ct) {
    int o0 = (ct0 + ct) * 16 + 4 * g;
    float4 bv = *(const float4*)&bias[o0];
    float v[4] = {acc[ct][0] + bv.x, acc[ct][1] + bv.y, acc[ct][2] + bv.z, acc[ct][3] + bv.w};
    if (RELU) { v[0] = fmaxf(v[0], 0.f); v[1] = fmaxf(v[1], 0.f); v[2] = fmaxf(v[2], 0.f); v[3] = fmaxf(v[3], 0.f); }
    if (OUTMODE == 0) {
      float4 r = {v[0], v[1], v[2], v[3]};
      *(float4*)&dstF[((size_t)b * MM + srow) * outld + o0] = r;
    } else if (OUTMODE == 1) {
      uint2 pk;
      pk.x = cvtpk(v[0], v[1]);
      pk.y = cvtpk(v[2], v[3]);
      *(uint2*)&dstB[((size_t)b * MM + srow) * outld + o0] = pk;
    } else {
      #pragma unroll
      for (int r = 0; r < 4; ++r)
        dstF[((size_t)b * rows + o0 + r) * MM + srow] = v[r];
    }
  }
}

// ---------------- merged BN stats: blocks 0..63 fg partials, 64..193 H channels ----------------
__global__ __launch_bounds__(256) void k_stats(const float* __restrict__ FGraw,
                                               float* __restrict__ FGP,
                                               const float* __restrict__ Hraw,
                                               const float* __restrict__ gh,
                                               const float* __restrict__ beh,
                                               float* __restrict__ abh) {
  int t = threadIdx.x;
  if (blockIdx.x < 64) {
    __shared__ float red[4][64][2];
    int c = t & 63, rq = t >> 6;
    int blk = blockIdx.x;
    float s = 0.f, s2 = 0.f;
    for (int k = 0; k < 64; ++k) {
      int r = blk * 256 + rq + 4 * k;
      float v = FGraw[(size_t)r * 64 + c];
      s += v; s2 += v * v;
    }
    red[rq][c][0] = s; red[rq][c][1] = s2;
    __syncthreads();
    if (t < 64) {
      float a = 0.f, a2 = 0.f;
      #pragma unroll
      for (int q = 0; q < 4; ++q) { a += red[q][t][0]; a2 += red[q][t][1]; }
      FGP[((size_t)blk * 64 + t) * 2] = a; FGP[((size_t)blk * 64 + t) * 2 + 1] = a2;
    }
  } else {
    int o = blockIdx.x - 64;  // < 130
    float s = 0.f, s2 = 0.f;
    for (int b = 0; b < NB; ++b) {
      const float* r = Hraw + ((size_t)b * 144 + o) * MM;
      for (int m = t; m < MM; m += 256) { float v = r[m]; s += v; s2 += v * v; }
    }
    __shared__ float rs[256], rs2[256];
    rs[t] = s; rs2[t] = s2;
    __syncthreads();
    for (int off = 128; off > 0; off >>= 1) {
      if (t < off) { rs[t] += rs[t + off]; rs2[t] += rs2[t + off]; }
      __syncthreads();
    }
    if (t == 0) {
      float cnt = 16384.0f;
      float mean = rs[0] / cnt, var = rs2[0] / cnt - mean * mean;
      float alpha = gh[o] * rsqrtf(var + EPSBN);
      abh[o * 2] = alpha; abh[o * 2 + 1] = beh[o] - mean * alpha;
    }
  }
}

// ---------------- merged cvt: blocks 0..511 FG (inline finalize), 512..2815 H ----------------
__global__ __launch_bounds__(256) void k_cvt(const float* __restrict__ FGraw,
                                             const float* __restrict__ FGP,
                                             const float* __restrict__ gf, const float* __restrict__ bef,
                                             const float* __restrict__ gg, const float* __restrict__ beg,
                                             unsigned short* __restrict__ FGT,
                                             const float* __restrict__ Hraw,
                                             const float* __restrict__ abh,
                                             unsigned short* __restrict__ HBo) {
  int t = threadIdx.x;
  if (blockIdx.x < 512) {
    __shared__ float sab[128];
    if (t < 64) {
      float s = 0.f, s2 = 0.f;
      for (int blk = 0; blk < 64; ++blk) {
        s += FGP[((size_t)blk * 64 + t) * 2];
        s2 += FGP[((size_t)blk * 64 + t) * 2 + 1];
      }
      float cnt = 16384.f;
      float mean = s / cnt, var = s2 / cnt - mean * mean;
      float gv = (t < 32) ? gf[t] : gg[t - 32];
      float bv = (t < 32) ? bef[t] : beg[t - 32];
      float alpha = gv * rsqrtf(var + EPSBN);
      sab[t * 2] = alpha; sab[t * 2 + 1] = bv - mean * alpha;
    }
    __syncthreads();
    int i = blockIdx.x * 256 + t;  // < 131072
    int row = i >> 3, c0 = (i & 7) * 8;
    float sc = (c0 < 32) ? LOG2E : 1.0f;
    float vv[8];
    float4 u0 = *(const float4*)&FGraw[(size_t)row * 64 + c0];
    float4 u1 = *(const float4*)&FGraw[(size_t)row * 64 + c0 + 4];
    vv[0] = u0.x; vv[1] = u0.y; vv[2] = u0.z; vv[3] = u0.w;
    vv[4] = u1.x; vv[5] = u1.y; vv[6] = u1.z; vv[7] = u1.w;
    uint4 pk;
    unsigned pw[4];
    #pragma unroll
    for (int h = 0; h < 4; ++h) {
      int c = c0 + 2 * h;
      float a0 = sab[c * 2] * sc, b0 = sab[c * 2 + 1] * sc;
      float a1 = sab[(c + 1) * 2] * sc, b1 = sab[(c + 1) * 2 + 1] * sc;
      float x0 = fmaxf(fmaf(a0, vv[2 * h], b0), 0.f);
      float x1 = fmaxf(fmaf(a1, vv[2 * h + 1], b1), 0.f);
      pw[h] = cvtpk(x0, x1);
    }
    pk.x = pw[0]; pk.y = pw[1]; pk.z = pw[2]; pk.w = pw[3];
    *(uint4*)&FGT[(size_t)row * 64 + c0] = pk;
  } else {
    int i = (blockIdx.x - 512) * 256 + t;  // (b*144 + c)*1024 + m4
    int m4 = i & 1023; int c = (i >> 10) % 144; int b = i / (144 * 1024);
    ushort4 ov = {0, 0, 0, 0};
    if (c < 130) {
      float4 v = *(const float4*)&Hraw[((size_t)b * 144 + c) * MM + m4 * 4];
      float a = abh[c * 2], be = abh[c * 2 + 1];
      ov.x = f2bf(fmaxf(fmaf(a, v.x, be), 0.f));
      ov.y = f2bf(fmaxf(fmaf(a, v.y, be), 0.f));
      ov.z = f2bf(fmaxf(fmaf(a, v.z, be), 0.f));
      ov.w = f2bf(fmaxf(fmaf(a, v.w, be), 0.f));
    }
    *(ushort4*)&HBo[((size_t)b * 144 + c) * MM + m4 * 4] = ov;
  }
}

// ---------------- K-LSE: S in log2 domain (F pre-scaled); defer-max online ----------------
__global__ __launch_bounds__(256) void k_zlse(const unsigned short* __restrict__ FGT,
                                              float* __restrict__ LSEP) {
  int t = threadIdx.x; int w = t >> 6; int l = t & 63;
  int b = blockIdx.z; int ms = blockIdx.y;
  int n0 = blockIdx.x * 64 + w * 16;
  int lm = l & 15, g = l >> 4;
  f32x4 z4 = {0.f, 0.f, 0.f, 0.f};
  short8 af = *(const short8*)&FGT[((size_t)b * MM + n0 + lm) * 64 + 32 + 8 * g];
  float rm[4], zz[4];
  #pragma unroll
  for (int r = 0; r < 4; ++r) { rm[r] = -__builtin_inff(); zz[r] = 0.f; }
  for (int it = 0; it < 16; ++it) {
    int m0 = ms * 1024 + it * 64;
    short8 bfr[4];
    #pragma unroll
    for (int mi = 0; mi < 4; ++mi)
      bfr[mi] = *(const short8*)&FGT[((size_t)b * MM + m0 + mi * 16 + lm) * 64 + 8 * g];
    f32x4 d[4];
    #pragma unroll
    for (int mi = 0; mi < 4; ++mi) d[mi] = MFMA16(af, bfr[mi], z4);
    #pragma unroll
    for (int r = 0; r < 4; ++r) {
      float tm = fmaxf(fmaxf(d[0][r], d[1][r]), fmaxf(d[2][r], d[3][r]));
      float nm = fmaxf(rm[r], tm);
      zz[r] = zz[r] * exp2f(rm[r] - nm)
            + exp2f(d[0][r] - nm) + exp2f(d[1][r] - nm)
            + exp2f(d[2][r] - nm) + exp2f(d[3][r] - nm);
      rm[r] = nm;
    }
  }
  #pragma unroll
  for (int off = 1; off < 16; off <<= 1) {
    #pragma unroll
    for (int r = 0; r < 4; ++r) {
      float om = __shfl_xor(rm[r], off);
      float oz = __shfl_xor(zz[r], off);
      float nm = fmaxf(rm[r], om);
      zz[r] = zz[r] * exp2f(rm[r] - nm) + oz * exp2f(om - nm);
      rm[r] = nm;
    }
  }
  if (lm == 0) {
    #pragma unroll
    for (int r = 0; r < 4; ++r) {
      int n = n0 + 4 * g + r;
      size_t idx = ((size_t)ms * 16384 + (size_t)b * MM + n) * 2;
      LSEP[idx] = rm[r]; LSEP[idx + 1] = zz[r];
    }
  }
}

// ---------------- merge LSE partials ----------------
__global__ __launch_bounds__(256) void k_lsered(const float* __restrict__ LSEP,
                                                float* __restrict__ LSE) {
  int bn = blockIdx.x * 256 + threadIdx.x;  // < 16384
  float rm = -__builtin_inff(), zz = 0.f;
  #pragma unroll
  for (int ms = 0; ms < 4; ++ms) {
    float m = LSEP[((size_t)ms * 16384 + bn) * 2];
    float z = LSEP[((size_t)ms * 16384 + bn) * 2 + 1];
    float nm = fmaxf(rm, m);
    zz = zz * exp2f(rm - nm) + z * exp2f(m - nm);
    rm = nm;
  }
  LSE[bn] = rm + log2f(zz);
}

// ---------------- K-O: MFMA O-pass, LDS-staged H with conflict-free read layout ----------------
// Hs layout per buffer: ct-subtile major; short offset = ct*512 + g*128 + lm*8
// => wave read for subtile ct is CONTIGUOUS 1KB at ct*512 + lane*8 (zero read conflicts).
__global__ __launch_bounds__(256) void k_omfma(const unsigned short* __restrict__ FGT,
                                               const unsigned short* __restrict__ HB,
                                               const float* __restrict__ LSE,
                                               unsigned short* __restrict__ Opart) {
  __shared__ __align__(16) unsigned short Hs[2][9 * 512];  // 2 x 9KB
  int t = threadIdx.x; int w = t >> 6; int l = t & 63;
  int b = blockIdx.y; int split = blockIdx.z;
  int lm = l & 15, g = l >> 4;
  int mcol0 = blockIdx.x * 128 + w * 32 + lm;
  int mcol1 = mcol0 + 16;
  f32x4 z4 = {0.f, 0.f, 0.f, 0.f};
  short8 Ff0 = *(const short8*)&FGT[((size_t)b * MM + mcol0) * 64 + 8 * g];
  short8 Ff1 = *(const short8*)&FGT[((size_t)b * MM + mcol1) * 64 + 8 * g];
  f32x4 acc0[9], acc1[9];
  #pragma unroll
  for (int ct = 0; ct < 9; ++ct) { acc0[ct] = z4; acc1[ct] = z4; }
  const int nchunks = (split < 2) ? 22 : 21;
  const int startc = split * 21 + ((split < 2) ? split : 2);
  const int start = startc * 32;
  const unsigned short* gptr = FGT + ((size_t)b * MM + lm) * 64 + 32 + 8 * g;
  const unsigned short* hsrc = HB + (size_t)b * 144 * MM;
  const float* lbase = LSE + (size_t)b * MM + 4 * g;
  int src01 = lm + 16 * (2 * (g & 1));
  int src23 = src01 + 16;
  bool hi = g >= 2;
  // staging: 576 uint4 items; item (ch, sg) -> LDS short offset (ch>>4)*512 + sg*128 + (ch&15)*8
  int sidx0 = t, sidx1 = t + 256, sidx2 = t + 512;
  int ch0 = sidx0 >> 2, sg0 = sidx0 & 3;
  int ch1 = sidx1 >> 2, sg1 = sidx1 & 3;
  int ch2 = (sidx2 < 576) ? (sidx2 >> 2) : 0;
  int sg2 = sidx2 & 3;
  bool has2 = sidx2 < 576;
  int d0 = (ch0 >> 4) * 512 + sg0 * 128 + (ch0 & 15) * 8;
  int d1 = (ch1 >> 4) * 512 + sg1 * 128 + (ch1 & 15) * 8;
  int d2 = (ch2 >> 4) * 512 + sg2 * 128 + (ch2 & 15) * 8;

  // preamble: stage chunk 0 into buf 0
  {
    uint4 r0 = *(const uint4*)(hsrc + (size_t)ch0 * MM + start + sg0 * 8);
    uint4 r1 = *(const uint4*)(hsrc + (size_t)ch1 * MM + start + sg1 * 8);
    uint4 r2 = has2 ? *(const uint4*)(hsrc + (size_t)ch2 * MM + start + sg2 * 8) : uint4{0,0,0,0};
    *(uint4*)&Hs[0][d0] = r0;
    *(uint4*)&Hs[0][d1] = r1;
    if (has2) *(uint4*)&Hs[0][d2] = r2;
  }
  // G/LSE for chunk 0
  short8 a0 = *(const short8*)(gptr + (size_t)start * 64);
  short8 a1 = *(const short8*)(gptr + (size_t)(start + 16) * 64);
  float4 l0 = *(const float4*)(lbase + start);
  float4 l1 = *(const float4*)(lbase + start + 16);
  __syncthreads();

  for (int it = 0; it < nchunks; ++it) {
    int n0 = start + it * 32;
    int cur = it & 1;
    bool more = (it + 1 < nchunks);
    int n1 = more ? (n0 + 32) : start;
    // (A) issue global loads for NEXT H chunk into regs
    uint4 r0, r1, r2;
    if (more) {
      r0 = *(const uint4*)(hsrc + (size_t)ch0 * MM + n1 + sg0 * 8);
      r1 = *(const uint4*)(hsrc + (size_t)ch1 * MM + n1 + sg1 * 8);
      if (has2) r2 = *(const uint4*)(hsrc + (size_t)ch2 * MM + n1 + sg2 * 8);
    }
    // next G/LSE into regs
    short8 na0 = *(const short8*)(gptr + (size_t)n1 * 64);
    short8 na1 = *(const short8*)(gptr + (size_t)(n1 + 16) * 64);
    float4 nl0 = *(const float4*)(lbase + n1);
    float4 nl1 = *(const float4*)(lbase + n1 + 16);
    // (B) compute current chunk from LDS buf[cur] (contiguous 1KB per ct)
    short8 hf[9];
    #pragma unroll
    for (int ct = 0; ct < 9; ++ct)
      hf[ct] = *(const short8*)&Hs[cur][ct * 512 + l * 8];
    f32x4 s00 = MFMA16(a0, Ff0, z4);
    f32x4 s10 = MFMA16(a1, Ff0, z4);
    f32x4 s01 = MFMA16(a0, Ff1, z4);
    f32x4 s11 = MFMA16(a1, Ff1, z4);
    float le0[4] = {l0.x, l0.y, l0.z, l0.w};
    float le1[4] = {l1.x, l1.y, l1.z, l1.w};
    unsigned pk00[2], pk10[2], pk01[2], pk11[2];
    #pragma unroll
    for (int h2 = 0; h2 < 2; ++h2) {
      pk00[h2] = cvtpk(exp2f(s00[2*h2] - le0[2*h2]), exp2f(s00[2*h2+1] - le0[2*h2+1]));
      pk10[h2] = cvtpk(exp2f(s10[2*h2] - le1[2*h2]), exp2f(s10[2*h2+1] - le1[2*h2+1]));
      pk01[h2] = cvtpk(exp2f(s01[2*h2] - le0[2*h2]), exp2f(s01[2*h2+1] - le0[2*h2+1]));
      pk11[h2] = cvtpk(exp2f(s11[2*h2] - le1[2*h2]), exp2f(s11[2*h2+1] - le1[2*h2+1]));
    }
    unsigned a0w = (unsigned)__shfl((int)pk00[0], src01);
    unsigned b0w = (unsigned)__shfl((int)pk10[0], src01);
    unsigned a1w = (unsigned)__shfl((int)pk00[1], src01);
    unsigned b1w = (unsigned)__shfl((int)pk10[1], src01);
    unsigned a2w = (unsigned)__shfl((int)pk00[0], src23);
    unsigned b2w = (unsigned)__shfl((int)pk10[0], src23);
    unsigned a3w = (unsigned)__shfl((int)pk00[1], src23);
    unsigned b3w = (unsigned)__shfl((int)pk10[1], src23);
    union { unsigned u[4]; short8 s; } bu0;
    bu0.u[0] = hi ? b0w : a0w; bu0.u[1] = hi ? b1w : a1w;
    bu0.u[2] = hi ? b2w : a2w; bu0.u[3] = hi ? b3w : a3w;
    short8 bfrag0 = bu0.s;
    unsigned c0w = (unsigned)__shfl((int)pk01[0], src01);
    unsigned d0w = (unsigned)__shfl((int)pk11[0], src01);
    unsigned c1w = (unsigned)__shfl((int)pk01[1], src01);
    unsigned d1w = (unsigned)__shfl((int)pk11[1], src01);
    unsigned c2w = (unsigned)__shfl((int)pk01[0], src23);
    unsigned d2w = (unsigned)__shfl((int)pk11[0], src23);
    unsigned c3w = (unsigned)__shfl((int)pk01[1], src23);
    unsigned d3w = (unsigned)__shfl((int)pk11[1], src23);
    union { unsigned u[4]; short8 s; } bu1;
    bu1.u[0] = hi ? d0w : c0w; bu1.u[1] = hi ? d1w : c1w;
    bu1.u[2] = hi ? d2w : c2w; bu1.u[3] = hi ? d3w : c3w;
    short8 bfrag1 = bu1.s;
    __builtin_amdgcn_s_setprio(1);
    #pragma unroll
    for (int ct = 0; ct < 9; ++ct) {
      acc0[ct] = MFMA16(hf[ct], bfrag0, acc0[ct]);
      acc1[ct] = MFMA16(hf[ct], bfrag1, acc1[ct]);
    }
    __builtin_amdgcn_s_setprio(0);
    // (C) write staged regs into the other buffer, (D) barrier
    if (more) {
      *(uint4*)&Hs[cur ^ 1][d0] = r0;
      *(uint4*)&Hs[cur ^ 1][d1] = r1;
      if (has2) *(uint4*)&Hs[cur ^ 1][d2] = r2;
    }
    a0 = na0; a1 = na1; l0 = nl0; l1 = nl1;
    __syncthreads();
  }

  unsigned short* op0 = Opart + (size_t)split * OPS_SH + ((size_t)b * MM + mcol0) * 132;
  unsigned short* op1 = Opart + (size_t)split * OPS_SH + ((size_t)b * MM + mcol1) * 132;
  #pragma unroll
  for (int ct = 0; ct < 9; ++ct) {
    int c0 = ct * 16 + 4 * g;
    if (c0 < 132) {
      uint2 p0, p1;
      p0.x = cvtpk(acc0[ct][0], acc0[ct][1]);
      p0.y = cvtpk(acc0[ct][2], acc0[ct][3]);
      p1.x = cvtpk(acc1[ct][0], acc1[ct][1]);
      p1.y = cvtpk(acc1[ct][2], acc1[ct][3]);
      *(uint2*)&op0[c0] = p0;
      *(uint2*)&op1[c0] = p1;
    }
  }
}

// ---------------- O reduce: A16 = bf16(gamma*sum(Oparts) + X) ----------------
__global__ __launch_bounds__(256) void k_ored(const unsigned short* __restrict__ Op,
                                              const unsigned short* __restrict__ X16,
                                              const float* __restrict__ gma,
                                              unsigned short* __restrict__ A16) {
  int i = blockIdx.x * 256 + threadIdx.x;  // < 327680
  int row = i / 20, c8 = i % 20;
  int c0 = c8 * 8;
  unsigned short* ap = A16 + (size_t)row * 160 + c0;
  if (c0 >= 136) {
    uint4 z = {0, 0, 0, 0};
    *(uint4*)ap = z;
    return;
  }
  float gm = gma[0];
  float ov[8] = {0.f, 0.f, 0.f, 0.f, 0.f, 0.f, 0.f, 0.f};
  #pragma unroll
  for (int s = 0; s < 6; ++s) {
    const unsigned short* base = Op + (size_t)s * OPS_SH + (size_t)row * 132 + c0;
    uint2 u = *(const uint2*)base;
    ov[0] += bf2f((unsigned short)(u.x & 0xffff));
    ov[1] += bf2f((unsigned short)(u.x >> 16));
    ov[2] += bf2f((unsigned short)(u.y & 0xffff));
    ov[3] += bf2f((unsigned short)(u.y >> 16));
    if (c0 + 4 < 132) {
      uint2 v = *(const uint2*)(base + 4);
      ov[4] += bf2f((unsigned short)(v.x & 0xffff));
      ov[5] += bf2f((unsigned short)(v.x >> 16));
      ov[6] += bf2f((unsigned short)(v.y & 0xffff));
      ov[7] += bf2f((unsigned short)(v.y >> 16));
    }
  }
  short8 xv = *(const short8*)(X16 + (size_t)row * 160 + c0);
  unsigned pw[4];
  #pragma unroll
  for (int h = 0; h < 4; ++h) {
    int ca = c0 + 2 * h, cb = c0 + 2 * h + 1;
    float xa = bf2f((unsigned short)xv[2 * h]);
    float xb = bf2f((unsigned short)xv[2 * h + 1]);
    float va = (ca < 132) ? (gm * ov[2 * h] + xa) : 0.f;
    float vb = (cb < 132) ? (gm * ov[2 * h + 1] + xb) : 0.f;
    pw[h] = (unsigned)f2bf(va) | ((unsigned)f2bf(vb) << 16);
  }
  uint4 pk = {pw[0], pw[1], pw[2], pw[3]};
  *(uint4*)ap = pk;
}

extern "C" void kernel_launch(void* const* d_in, const int* in_sizes, int n_in,
                              void* d_out, int out_size, void* d_ws, size_t ws_size,
                              hipStream_t stream) {
  const float* inp = (const float*)d_in[0];
  const float* Wa  = (const float*)d_in[1];
  const float* gna = (const float*)d_in[2];
  const float* bta = (const float*)d_in[3];
  const float* Wb  = (const float*)d_in[4];
  const float* gnb = (const float*)d_in[5];
  const float* btb = (const float*)d_in[6];
  const float* Wf  = (const float*)d_in[7];
  const float* bf  = (const float*)d_in[8];
  const float* gf  = (const float*)d_in[9];
  const float* bef = (const float*)d_in[10];
  const float* Wg  = (const float*)d_in[11];
  const float* bg  = (const float*)d_in[12];
  const float* gg  = (const float*)d_in[13];
  const float* beg = (const float*)d_in[14];
  const float* Wh  = (const float*)d_in[15];
  const float* bh  = (const float*)d_in[16];
  const float* gh  = (const float*)d_in[17];
  const float* beh = (const float*)d_in[18];
  const float* gamma = (const float*)d_in[19];
  const float* W1  = (const float*)d_in[20];
  const float* b1  = (const float*)d_in[21];
  const float* W2  = (const float*)d_in[22];
  const float* b2  = (const float*)d_in[23];
  float* out = (float*)d_out;

  float* ws = (float*)d_ws;
  float* DIST = ws + OFF_DIST;
  float* PM   = ws + OFF_PM;
  float* QM   = ws + OFF_QM;
  float* HRAW = ws + OFF_HRAW;
  float* FGRAW= ws + OFF_FGRAW;
  unsigned short* OP16 = (unsigned short*)(ws + OFF_OP);
  unsigned short* FGT = (unsigned short*)(ws + OFF_FGT);
  unsigned short* HBB = (unsigned short*)(ws + OFF_HB);
  unsigned short* A16 = (unsigned short*)(ws + OFF_A16);
  unsigned short* X16 = (unsigned short*)(ws + OFF_X16);
  unsigned short* Y1  = (unsigned short*)(ws + OFF_Y1);
  float* LSEB = ws + OFF_LSE;
  float* LSEP = ws + OFF_LSEP;
  float* STATS= ws + OFF_STATS;
  float* ABE  = ws + OFF_ABE;
  float* ABH  = ws + OFF_ABH;
  float* FGP  = ws + OFF_FGP;
  float* BIAS = ws + OFF_BIAS;
  unsigned short* W16 = (unsigned short*)(ws + OFF_W16);
  int*   KNNI = (int*)(ws + OFF_KNN);
  float* XN   = ws + OFF_XN;
  unsigned short* XR = (unsigned short*)(ws + OFF_XR);
  unsigned short* WPQ = (unsigned short*)(ws + OFF_WPQ);
  float* SQ   = ws + OFF_SQ;

  // 0. fused prep + normalize
  k_init<<<949, 256, 0, stream>>>(Wf, Wg, Wh, W1, W2, bf, bg, bh, b1, b2, Wa, Wb, W16, BIAS, WPQ,
                                  inp, XN, XR, SQ);
  // 1-2. fp32 dist 128x64 (exact kNN path), knn
  k_dist<<<dim3(16, 8, 4), 256, 0, stream>>>(XN, SQ, DIST);
  k_knn<<<4096, 64, 0, stream>>>(DIST, KNNI);
  // 3. P/Q MFMA (overwrites DIST) ; 4-5. edge BN ; 6. apply -> X16
  k_pqm<<<dim3(16, 4, 8), 256, 0, stream>>>(XR, WPQ, PM, QM);
  k_edge_stats<<<dim3(16, 4, 2), 256, 0, stream>>>(PM, QM, KNNI, STATS);
  k_edge_fin<<<2, 256, 0, stream>>>(STATS, gna, bta, gnb, btb, ABE);
  k_edge_apply<<<dim3(1024, 4), 256, 0, stream>>>(PM, QM, KNNI, ABE, X16);
  // 7. f+g conv (f32 m-major raw) and h conv (f32 ch-major raw), over dead PM/QM region
  k_convm<5, 2, 0, false><<<dim3(64, 2, 4), 256, 0, stream>>>(X16, W16 + W16_FG, BIAS + B_FG, FGRAW, nullptr, 64, 0);
  k_convm<5, 3, 2, false><<<dim3(64, 3, 4), 256, 0, stream>>>(X16, W16 + W16_H, BIAS + B_H, HRAW, nullptr, 0, 144);
  // 8. merged BN stats + merged cvt
  k_stats<<<194, 256, 0, stream>>>(FGRAW, FGP, HRAW, gh, beh, ABH);
  k_cvt<<<2816, 256, 0, stream>>>(FGRAW, FGP, gf, bef, gg, beg, FGT, HRAW, ABH, HBB);
  // 9. LSE ; 10. O-pass (conflict-free LDS layout) ; 11. reduce -> A16
  k_zlse<<<dim3(64, 4, 4), 256, 0, stream>>>(FGT, LSEP);
  k_lsered<<<64, 256, 0, stream>>>(LSEP, LSEB);
  k_omfma<<<dim3(32, 4, 6), 256, 0, stream>>>(FGT, HBB, LSEB, OP16);
  k_ored<<<1280, 256, 0, stream>>>(OP16, X16, gamma, A16);
  // 12-13. final convs (MFMA)
  k_convm<5, 8, 1, true><<<dim3(64, 2, 4), 256, 0, stream>>>(A16, W16 + W16_C1, BIAS + B_C1, nullptr, Y1, 256, 0);
  k_convm<8, 4, 2, true><<<dim3(64, 2, 4), 256, 0, stream>>>(Y1, W16 + W16_C2, BIAS + B_C2, out, nullptr, 0, 128);
}

// Round 15
// 306.230 us; speedup vs baseline: 1.0363x; 1.0022x over previous
//
#include <hip/hip_runtime.h>

namespace {
constexpr int NB = 4;      // batch
constexpr int CI = 128;    // input channels
constexpr int NP = 1024;   // points
constexpr int MM = 4096;   // N*UP
constexpr float EPSBN = 1e-5f;
constexpr float LOG2E = 1.4426950408889634f;

constexpr size_t OPS_SH = 2162688;       // Opart split stride in SHORTS (B*MM*132)
// workspace offsets (floats)
constexpr size_t OFF_OP   = 0;           // 6 bf16 splits = 6488064 floats (overlaid: DIST / Pm,Qm / Hraw,FGraw / Y1)
constexpr size_t OFF_DIST = 0;           // 4194304
constexpr size_t OFF_PM   = 0;           // 2097152
constexpr size_t OFF_QM   = 2097152;     // 2097152
constexpr size_t OFF_HRAW = 0;           // 2359296 (B,144,MM) f32
constexpr size_t OFF_FGRAW= 2359296;     // 1048576 (B,MM,64) f32  -> ends 3407872
constexpr size_t OFF_Y1   = 0;           // (B,MM,256) bf16 = 2097152 floats
constexpr size_t OFF_FGT  = 6488064;     // (B,MM,64) bf16 = 524288 floats
constexpr size_t OFF_HB   = 7012352;     // (B,144,MM) bf16 = 1179648 floats
constexpr size_t OFF_A16  = 6488064;     // (B,MM,160) bf16 = 1310720 floats (over FGT/HB after omfma)
constexpr size_t OFF_X16  = 8192000;     // (B,MM,160) bf16 = 1310720 floats
constexpr size_t OFF_LSE  = 9502720;     // 16384
constexpr size_t OFF_LSEP = 9519104;     // 131072
constexpr size_t OFF_STATS= 9650176;     // 65536
constexpr size_t OFF_ABE  = 9715712;     // 1024
constexpr size_t OFF_ABH  = 9716864;     // 512
constexpr size_t OFF_FGP  = 9717376;     // 8192
constexpr size_t OFF_BIAS = 9725568;     // 640
constexpr size_t OFF_W16  = 9726208;     // 53504 (107008 shorts)
constexpr size_t OFF_KNN  = 9779712;     // 73728 ints
constexpr size_t OFF_XN   = 9853440;     // (B,128,1024) f32 = 524288 (normalized, ch-major, for fp32 dist)
constexpr size_t OFF_SQ   = 10377728;    // 4096
constexpr size_t OFF_XR   = 10381824;    // (B,1024,128) bf16 raw = 262144 floats
constexpr size_t OFF_WPQ  = 10643968;    // 65536 floats (131072 shorts) -> ends 10709504
// W16 sub-offsets (shorts)
constexpr size_t W16_FG = 0;       // 64x160
constexpr size_t W16_H  = 10240;   // 144x160
constexpr size_t W16_C1 = 33280;   // 256x160
constexpr size_t W16_C2 = 74240;   // 128x256
// BIAS sub-offsets (floats)
constexpr size_t B_FG = 0, B_H = 64, B_C1 = 208, B_C2 = 464;
} // namespace

typedef __attribute__((ext_vector_type(8))) short short8;
typedef __attribute__((ext_vector_type(4))) float f32x4;
#define MFMA16(A, B, C) __builtin_amdgcn_mfma_f32_16x16x32_bf16(A, B, C, 0, 0, 0)

__device__ inline unsigned short f2bf(float x) {
  unsigned int u = __float_as_uint(x);
  unsigned int r = u + 0x7fff + ((u >> 16) & 1);
  return (unsigned short)(r >> 16);
}
__device__ inline float bf2f(unsigned short s) {
  return __uint_as_float(((unsigned int)s) << 16);
}
__device__ inline unsigned cvtpk(float lo, float hi) {
  unsigned r;
  asm("v_cvt_pk_bf16_f32 %0, %1, %2" : "=v"(r) : "v"(lo), "v"(hi));
  return r;
}

// ---------------- K0: fused weight-prep + normalize ----------------
__global__ __launch_bounds__(256) void k_init(const float* __restrict__ Wf, const float* __restrict__ Wg,
                                              const float* __restrict__ Wh, const float* __restrict__ W1,
                                              const float* __restrict__ W2, const float* __restrict__ bf,
                                              const float* __restrict__ bg, const float* __restrict__ bh,
                                              const float* __restrict__ b1, const float* __restrict__ b2,
                                              const float* __restrict__ Wa, const float* __restrict__ Wb,
                                              unsigned short* __restrict__ W16, float* __restrict__ BIAS,
                                              unsigned short* __restrict__ WPQ,
                                              const float* __restrict__ x,
                                              float* __restrict__ xn,
                                              unsigned short* __restrict__ XR,
                                              float* __restrict__ sq) {
  if (blockIdx.x < 933) {
    int i = blockIdx.x * 256 + threadIdx.x;
    if (i < 107008) {
      float v = 0.f;
      if (i < 10240) { int o = i / 160, c = i % 160; if (c < 130) v = (o < 32) ? Wf[o * 130 + c] : Wg[(o - 32) * 130 + c]; }
      else if (i < 33280) { int r = i - 10240; int o = r / 160, c = r % 160; if (o < 130 && c < 130) v = Wh[o * 130 + c]; }
      else if (i < 74240) { int r = i - 33280; int o = r / 160, c = r % 160; if (c < 130) v = W1[o * 130 + c]; }
      else { int r = i - 74240; int o = r / 256, c = r % 256; v = W2[o * 256 + c]; }
      W16[i] = f2bf(v);
    } else if (i < 107648) {
      int j = i - 107008; float v = 0.f;
      if (j < 64) v = (j < 32) ? bf[j] : bg[j - 32];
      else if (j < 208) { int c = j - 64; if (c < 130) v = bh[c]; }
      else if (j < 464) v = b1[j - 208];
      else if (j < 592) v = b2[j - 464];
      BIAS[j] = v;
    } else if (i < 238720) {
      int j = i - 107648;
      int e = j >> 16;
      int rem = j & 65535;
      int pq = rem >> 15;
      int rr = rem & 32767;
      int o = rr >> 7, c = rr & 127;
      const float* W = e ? Wb : Wa;
      float w1 = W[o * 256 + c], w2 = W[o * 256 + 128 + c];
      float v = pq ? w2 : (w1 - w2);
      WPQ[j] = f2bf(v);
    }
  } else {
    int t = (blockIdx.x - 933) * 256 + threadIdx.x;   // b*1024+n
    int b = t >> 10, n = t & 1023;
    const float* xb = x + (size_t)b * CI * NP + n;
    float ss = 0.f;
    #pragma unroll 4
    for (int c = 0; c < CI; ++c) { float v = xb[(size_t)c * NP]; ss += v * v; }
    float inv = 1.f / fmaxf(sqrtf(ss), 1e-12f);
    float* xo = xn + (size_t)b * CI * NP + n;
    float s2 = 0.f;
    for (int c0 = 0; c0 < 128; c0 += 8) {
      unsigned rw[4];
      #pragma unroll
      for (int j = 0; j < 4; ++j) {
        float va = xb[(size_t)(c0 + 2 * j) * NP];
        float vb = xb[(size_t)(c0 + 2 * j + 1) * NP];
        float na = va * inv, nb = vb * inv;
        s2 += na * na + nb * nb;
        xo[(size_t)(c0 + 2 * j) * NP] = na;
        xo[(size_t)(c0 + 2 * j + 1) * NP] = nb;
        rw[j] = (unsigned)f2bf(va) | ((unsigned)f2bf(vb) << 16);
      }
      uint4 r4 = {rw[0], rw[1], rw[2], rw[3]};
      *(uint4*)&XR[(size_t)t * 128 + c0] = r4;
    }
    sq[t] = s2;
  }
}

// ---------------- K2: pairwise distance, fp32 128x64 tile (exact kNN path; same fp order) ----------------
__global__ __launch_bounds__(256) void k_dist(const float* __restrict__ xn,
                                              const float* __restrict__ sq,
                                              float* __restrict__ dist) {
  __shared__ float As[32][132], Bs[32][68];
  int t = threadIdx.x;
  int m0 = blockIdx.x * 64, n0 = blockIdx.y * 128, b = blockIdx.z;
  int mg = t & 15, ng = t >> 4;
  float acc[8][4];
  #pragma unroll
  for (int i = 0; i < 8; ++i)
    #pragma unroll
    for (int j = 0; j < 4; ++j) acc[i][j] = 0.f;
  for (int cc = 0; cc < 128; cc += 32) {
    __syncthreads();
    for (int idx = t; idx < 4096; idx += 256) {
      int c = idx >> 7, j = idx & 127;
      As[c][j] = xn[((size_t)b * CI + cc + c) * NP + n0 + j];
    }
    for (int idx = t; idx < 2048; idx += 256) {
      int c = idx >> 6, j = idx & 63;
      Bs[c][j] = xn[((size_t)b * CI + cc + c) * NP + m0 + j];
    }
    __syncthreads();
    #pragma unroll
    for (int c = 0; c < 32; ++c) {
      float4 a0 = *(const float4*)&As[c][ng * 8];
      float4 a1 = *(const float4*)&As[c][ng * 8 + 4];
      float4 b0 = *(const float4*)&Bs[c][mg * 4];
      float av[8] = {a0.x, a0.y, a0.z, a0.w, a1.x, a1.y, a1.z, a1.w};
      float bv[4] = {b0.x, b0.y, b0.z, b0.w};
      #pragma unroll
      for (int i = 0; i < 8; ++i)
        #pragma unroll
        for (int j = 0; j < 4; ++j) acc[i][j] += av[i] * bv[j];
    }
  }
  #pragma unroll
  for (int i = 0; i < 8; ++i) {
    int n = n0 + ng * 8 + i;
    float sn = sq[b * NP + n];
    int mb = m0 + mg * 4;
    float4 r;
    r.x = sn + sq[b * NP + mb + 0] - 2.f * acc[i][0];
    r.y = sn + sq[b * NP + mb + 1] - 2.f * acc[i][1];
    r.z = sn + sq[b * NP + mb + 2] - 2.f * acc[i][2];
    r.w = sn + sq[b * NP + mb + 3] - 2.f * acc[i][3];
    *(float4*)&dist[((size_t)b * NP + n) * NP + mb] = r;
  }
}

// ---------------- K3: top-18 nearest per row ----------------
__global__ __launch_bounds__(64) void k_knn(const float* __restrict__ dist,
                                            int* __restrict__ knn) {
  int row = blockIdx.x;
  int l = threadIdx.x;
  const float* dr = dist + (size_t)row * NP;
  float d[16];
  #pragma unroll
  for (int i = 0; i < 16; ++i) d[i] = dr[l + 64 * i];
  for (int s = 0; s < 18; ++s) {
    float best = __builtin_inff(); int bslot = -1;
    #pragma unroll
    for (int i = 0; i < 16; ++i) if (d[i] < best) { best = d[i]; bslot = i; }
    int bidx = (bslot >= 0) ? (l + 64 * bslot) : 0x7fffffff;
    float bd = best; int bi = bidx;
    #pragma unroll
    for (int off = 32; off > 0; off >>= 1) {
      float od = __shfl_xor(bd, off);
      int   oi = __shfl_xor(bi, off);
      if (od < bd || (od == bd && oi < bi)) { bd = od; bi = oi; }
    }
    if (l == 0) knn[row * 18 + s] = bi;
    if ((bi & 63) == l) d[bi >> 6] = __builtin_inff();
  }
}

// ---------------- K4: P/Q pre-GEMMs via MFMA, m-major f32 out ----------------
__global__ __launch_bounds__(256) void k_pqm(const unsigned short* __restrict__ XR,
                                             const unsigned short* __restrict__ WPQ,
                                             float* __restrict__ Pm,
                                             float* __restrict__ Qm) {
  int t = threadIdx.x; int w = t >> 6; int l = t & 63;
  int lm = l & 15, g = l >> 4;
  int nt = blockIdx.x, oq = blockIdx.y, z = blockIdx.z;
  int e = z >> 2, b = z & 3;
  int srow = nt * 64 + w * 16 + lm;
  const unsigned short* sp = XR + ((size_t)b * 1024 + srow) * 128 + 8 * g;
  const unsigned short* wpp = WPQ + ((size_t)(e * 2 + 0) * 256 + oq * 64 + lm) * 128 + 8 * g;
  const unsigned short* wqq = WPQ + ((size_t)(e * 2 + 1) * 256 + oq * 64 + lm) * 128 + 8 * g;
  f32x4 accp[4], accq[4];
  #pragma unroll
  for (int i = 0; i < 4; ++i) { accp[i] = {0.f, 0.f, 0.f, 0.f}; accq[i] = {0.f, 0.f, 0.f, 0.f}; }
  #pragma unroll
  for (int cc = 0; cc < 4; ++cc) {
    short8 bfr = *(const short8*)(sp + cc * 32);
    #pragma unroll
    for (int ct = 0; ct < 4; ++ct) {
      short8 ap = *(const short8*)(wpp + (size_t)ct * 16 * 128 + cc * 32);
      accp[ct] = MFMA16(ap, bfr, accp[ct]);
      short8 aq = *(const short8*)(wqq + (size_t)ct * 16 * 128 + cc * 32);
      accq[ct] = MFMA16(aq, bfr, accq[ct]);
    }
  }
  int eb = e * 4 + b;
  #pragma unroll
  for (int ct = 0; ct < 4; ++ct) {
    int o0 = oq * 64 + ct * 16 + 4 * g;
    float4 rp = {accp[ct][0], accp[ct][1], accp[ct][2], accp[ct][3]};
    float4 rq = {accq[ct][0], accq[ct][1], accq[ct][2], accq[ct][3]};
    *(float4*)&Pm[((size_t)eb * 1024 + srow) * 256 + o0] = rp;
    *(float4*)&Qm[((size_t)eb * 1024 + srow) * 256 + o0] = rq;
  }
}

// ---------------- K5: edge BN stats partials ----------------
__global__ __launch_bounds__(256) void k_edge_stats(const float* __restrict__ Pm,
                                                    const float* __restrict__ Qm,
                                                    const int* __restrict__ knn,
                                                    float* __restrict__ stats) {
  int o = threadIdx.x;
  int chunk = blockIdx.x, b = blockIdx.y, e = blockIdx.z;
  int eb = e * 4 + b;
  float s = 0.f, s2 = 0.f;
  for (int nn = 0; nn < 64; ++nn) {
    int n = chunk * 64 + nn;
    float p = Pm[((size_t)eb * 1024 + n) * 256 + o];
    const int* kn = knn + (b * 1024 + n) * 18;
    #pragma unroll
    for (int kk = 0; kk < 9; ++kk) {
      int j = kn[e ? 2 * kk : kk];
      float v = p + Qm[((size_t)eb * 1024 + j) * 256 + o];
      s += v; s2 += v * v;
    }
  }
  size_t idx = ((((size_t)e * 4 + b) * 16 + chunk) * 256 + o) * 2;
  stats[idx] = s; stats[idx + 1] = s2;
}

// ---------------- K6: finalize edge BN ----------------
__global__ __launch_bounds__(256) void k_edge_fin(const float* __restrict__ stats,
                                                  const float* __restrict__ gna, const float* __restrict__ bta,
                                                  const float* __restrict__ gnb, const float* __restrict__ btb,
                                                  float* __restrict__ ab) {
  int i = blockIdx.x * 256 + threadIdx.x;
  if (i >= 512) return;
  int e = i >> 8, o = i & 255;
  float s = 0.f, s2 = 0.f;
  for (int b = 0; b < 4; ++b)
    for (int ch = 0; ch < 16; ++ch) {
      size_t idx = ((((size_t)e * 4 + b) * 16 + ch) * 256 + o) * 2;
      s += stats[idx]; s2 += stats[idx + 1];
    }
  float cnt = 4.0f * 1024.0f * 9.0f;
  float mean = s / cnt;
  float var = s2 / cnt - mean * mean;
  float g = e ? gnb[o] : gna[o];
  float bt = e ? btb[o] : bta[o];
  float alpha = g * rsqrtf(var + EPSBN);
  ab[i * 2] = alpha; ab[i * 2 + 1] = bt - mean * alpha;
}

// ---------------- K7: edge apply + max-over-k -> X16 (B,MM,160) bf16 ----------------
__global__ __launch_bounds__(256) void k_edge_apply(const float* __restrict__ Pm,
                                                    const float* __restrict__ Qm,
                                                    const int* __restrict__ knn,
                                                    const float* __restrict__ ab,
                                                    unsigned short* __restrict__ X16) {
  __shared__ int knl[18];
  int t = threadIdx.x;
  int n = blockIdx.x, b = blockIdx.y;
  if (t < 18) knl[t] = knn[(b * 1024 + n) * 18 + t];
  __syncthreads();
  int e = t >> 7, oo = t & 127;
  int eb = e * 4 + b;
  const float* Pr = Pm + ((size_t)eb * 1024 + n) * 256;
  const float* Qb = Qm + (size_t)eb * 1024 * 256;
  float p0 = Pr[oo], p1 = Pr[oo + 128];
  float a0 = ab[(e * 256 + oo) * 2], be0 = ab[(e * 256 + oo) * 2 + 1];
  float a1 = ab[(e * 256 + oo + 128) * 2], be1 = ab[(e * 256 + oo + 128) * 2 + 1];
  float mx0 = -__builtin_inff(), mx1 = -__builtin_inff();
  #pragma unroll
  for (int kk = 0; kk < 9; ++kk) {
    int j = knl[e ? 2 * kk : kk];
    const float* Qr = Qb + (size_t)j * 256;
    mx0 = fmaxf(mx0, fmaf(a0, p0 + Qr[oo], be0));
    mx1 = fmaxf(mx1, fmaf(a1, p1 + Qr[oo + 128], be1));
  }
  int u0 = e << 1, u1 = (e << 1) | 1;
  X16[((size_t)b * MM + 4 * n + u0) * 160 + oo] = f2bf(fmaxf(mx0, 0.f));
  X16[((size_t)b * MM + 4 * n + u1) * 160 + oo] = f2bf(fmaxf(mx1, 0.f));
  if (t < 128) {
    int u = t >> 5, c = 128 + (t & 31);
    int gr = n >> 8;
    float v = (c == 128) ? ((gr < 2) ? -0.2f : 0.2f) : (c == 129) ? ((gr & 1) ? 0.2f : -0.2f) : 0.f;
    X16[((size_t)b * MM + 4 * n + u) * 160 + c] = f2bf(v);
  }
}

// ---------------- MFMA 1x1 conv ----------------
// OUTMODE 0: f32 m-major | 1: bf16 m-major | 2: f32 ch-major
template <int KSTEPS, int CTPER, int OUTMODE, bool RELU>
__global__ __launch_bounds__(256) void k_convm(const unsigned short* __restrict__ src,
                                               const unsigned short* __restrict__ W16,
                                               const float* __restrict__ bias,
                                               float* __restrict__ dstF,
                                               unsigned short* __restrict__ dstB,
                                               int outld, int rows) {
  constexpr int LD = KSTEPS * 32;
  int t = threadIdx.x; int w = t >> 6; int l = t & 63;
  int lm = l & 15, g = l >> 4;
  int b = blockIdx.z; int ct0 = blockIdx.y * CTPER;
  int srow = blockIdx.x * 64 + w * 16 + lm;
  const unsigned short* sp = src + ((size_t)b * MM + srow) * LD + 8 * g;
  const unsigned short* wp = W16 + ((size_t)ct0 * 16 + lm) * LD + 8 * g;
  f32x4 acc[CTPER];
  #pragma unroll
  for (int i = 0; i < CTPER; ++i) acc[i] = {0.f, 0.f, 0.f, 0.f};
  #pragma unroll
  for (int cc = 0; cc < KSTEPS; ++cc) {
    short8 bfr = *(const short8*)(sp + cc * 32);
    #pragma unroll
    for (int ct = 0; ct < CTPER; ++ct) {
      short8 af = *(const short8*)(wp + (size_t)ct * 16 * LD + cc * 32);
      acc[ct] = MFMA16(af, bfr, acc[ct]);
    }
  }
  #pragma unroll
  for (int ct = 0; ct < CTPER; ++ct) {
    int o0 = (ct0 + ct) * 16 + 4 * g;
    float4 bv = *(const float4*)&bias[o0];
    float v[4] = {acc[ct][0] + bv.x, acc[ct][1] + bv.y, acc[ct][2] + bv.z, acc[ct][3] + bv.w};
    if (RELU) { v[0] = fmaxf(v[0], 0.f); v[1] = fmaxf(v[1], 0.f); v[2] = fmaxf(v[2], 0.f); v[3] = fmaxf(v[3], 0.f); }
    if (OUTMODE == 0) {
      float4 r = {v[0], v[1], v[2], v[3]};
      *(float4*)&dstF[((size_t)b * MM + srow) * outld + o0] = r;
    } else if (OUTMODE == 1) {
      uint2 pk;
      pk.x = cvtpk(v[0], v[1]);
      pk.y = cvtpk(v[2], v[3]);
      *(uint2*)&dstB[((size_t)b * MM + srow) * outld + o0] = pk;
    } else {
      #pragma unroll
      for (int r = 0; r < 4; ++r)
        dstF[((size_t)b * rows + o0 + r) * MM + srow] = v[r];
    }
  }
}

// ---------------- merged BN stats: blocks 0..63 fg partials, 64..193 H channels ----------------
__global__ __launch_bounds__(256) void k_stats(const float* __restrict__ FGraw,
                                               float* __restrict__ FGP,
                                               const float* __restrict__ Hraw,
                                               const float* __restrict__ gh,
                                               const float* __restrict__ beh,
                                               float* __restrict__ abh) {
  int t = threadIdx.x;
  if (blockIdx.x < 64) {
    __shared__ float red[4][64][2];
    int c = t & 63, rq = t >> 6;
    int blk = blockIdx.x;
    float s = 0.f, s2 = 0.f;
    for (int k = 0; k < 64; ++k) {
      int r = blk * 256 + rq + 4 * k;
      float v = FGraw[(size_t)r * 64 + c];
      s += v; s2 += v * v;
    }
    red[rq][c][0] = s; red[rq][c][1] = s2;
    __syncthreads();
    if (t < 64) {
      float a = 0.f, a2 = 0.f;
      #pragma unroll
      for (int q = 0; q < 4; ++q) { a += red[q][t][0]; a2 += red[q][t][1]; }
      FGP[((size_t)blk * 64 + t) * 2] = a; FGP[((size_t)blk * 64 + t) * 2 + 1] = a2;
    }
  } else {
    int o = blockIdx.x - 64;  // < 130
    float s = 0.f, s2 = 0.f;
    for (int b = 0; b < NB; ++b) {
      const float* r = Hraw + ((size_t)b * 144 + o) * MM;
      for (int m = t; m < MM; m += 256) { float v = r[m]; s += v; s2 += v * v; }
    }
    __shared__ float rs[256], rs2[256];
    rs[t] = s; rs2[t] = s2;
    __syncthreads();
    for (int off = 128; off > 0; off >>= 1) {
      if (t < off) { rs[t] += rs[t + off]; rs2[t] += rs2[t + off]; }
      __syncthreads();
    }
    if (t == 0) {
      float cnt = 16384.0f;
      float mean = rs[0] / cnt, var = rs2[0] / cnt - mean * mean;
      float alpha = gh[o] * rsqrtf(var + EPSBN);
      abh[o * 2] = alpha; abh[o * 2 + 1] = beh[o] - mean * alpha;
    }
  }
}

// ---------------- merged cvt: blocks 0..511 FG (inline finalize), 512..2815 H ----------------
__global__ __launch_bounds__(256) void k_cvt(const float* __restrict__ FGraw,
                                             const float* __restrict__ FGP,
                                             const float* __restrict__ gf, const float* __restrict__ bef,
                                             const float* __restrict__ gg, const float* __restrict__ beg,
                                             unsigned short* __restrict__ FGT,
                                             const float* __restrict__ Hraw,
                                             const float* __restrict__ abh,
                                             unsigned short* __restrict__ HBo) {
  int t = threadIdx.x;
  if (blockIdx.x < 512) {
    __shared__ float sab[128];
    if (t < 64) {
      float s = 0.f, s2 = 0.f;
      for (int blk = 0; blk < 64; ++blk) {
        s += FGP[((size_t)blk * 64 + t) * 2];
        s2 += FGP[((size_t)blk * 64 + t) * 2 + 1];
      }
      float cnt = 16384.f;
      float mean = s / cnt, var = s2 / cnt - mean * mean;
      float gv = (t < 32) ? gf[t] : gg[t - 32];
      float bv = (t < 32) ? bef[t] : beg[t - 32];
      float alpha = gv * rsqrtf(var + EPSBN);
      sab[t * 2] = alpha; sab[t * 2 + 1] = bv - mean * alpha;
    }
    __syncthreads();
    int i = blockIdx.x * 256 + t;  // < 131072
    int row = i >> 3, c0 = (i & 7) * 8;
    float sc = (c0 < 32) ? LOG2E : 1.0f;
    float vv[8];
    float4 u0 = *(const float4*)&FGraw[(size_t)row * 64 + c0];
    float4 u1 = *(const float4*)&FGraw[(size_t)row * 64 + c0 + 4];
    vv[0] = u0.x; vv[1] = u0.y; vv[2] = u0.z; vv[3] = u0.w;
    vv[4] = u1.x; vv[5] = u1.y; vv[6] = u1.z; vv[7] = u1.w;
    uint4 pk;
    unsigned pw[4];
    #pragma unroll
    for (int h = 0; h < 4; ++h) {
      int c = c0 + 2 * h;
      float a0 = sab[c * 2] * sc, b0 = sab[c * 2 + 1] * sc;
      float a1 = sab[(c + 1) * 2] * sc, b1 = sab[(c + 1) * 2 + 1] * sc;
      float x0 = fmaxf(fmaf(a0, vv[2 * h], b0), 0.f);
      float x1 = fmaxf(fmaf(a1, vv[2 * h + 1], b1), 0.f);
      pw[h] = cvtpk(x0, x1);
    }
    pk.x = pw[0]; pk.y = pw[1]; pk.z = pw[2]; pk.w = pw[3];
    *(uint4*)&FGT[(size_t)row * 64 + c0] = pk;
  } else {
    int i = (blockIdx.x - 512) * 256 + t;  // (b*144 + c)*1024 + m4
    int m4 = i & 1023; int c = (i >> 10) % 144; int b = i / (144 * 1024);
    ushort4 ov = {0, 0, 0, 0};
    if (c < 130) {
      float4 v = *(const float4*)&Hraw[((size_t)b * 144 + c) * MM + m4 * 4];
      float a = abh[c * 2], be = abh[c * 2 + 1];
      ov.x = f2bf(fmaxf(fmaf(a, v.x, be), 0.f));
      ov.y = f2bf(fmaxf(fmaf(a, v.y, be), 0.f));
      ov.z = f2bf(fmaxf(fmaf(a, v.z, be), 0.f));
      ov.w = f2bf(fmaxf(fmaf(a, v.w, be), 0.f));
    }
    *(ushort4*)&HBo[((size_t)b * 144 + c) * MM + m4 * 4] = ov;
  }
}

// ---------------- K-LSE: S in log2 domain (F pre-scaled); defer-max online ----------------
__global__ __launch_bounds__(256) void k_zlse(const unsigned short* __restrict__ FGT,
                                              float* __restrict__ LSEP) {
  int t = threadIdx.x; int w = t >> 6; int l = t & 63;
  int b = blockIdx.z; int ms = blockIdx.y;
  int n0 = blockIdx.x * 64 + w * 16;
  int lm = l & 15, g = l >> 4;
  f32x4 z4 = {0.f, 0.f, 0.f, 0.f};
  short8 af = *(const short8*)&FGT[((size_t)b * MM + n0 + lm) * 64 + 32 + 8 * g];
  float rm[4], zz[4];
  #pragma unroll
  for (int r = 0; r < 4; ++r) { rm[r] = -__builtin_inff(); zz[r] = 0.f; }
  for (int it = 0; it < 16; ++it) {
    int m0 = ms * 1024 + it * 64;
    short8 bfr[4];
    #pragma unroll
    for (int mi = 0; mi < 4; ++mi)
      bfr[mi] = *(const short8*)&FGT[((size_t)b * MM + m0 + mi * 16 + lm) * 64 + 8 * g];
    f32x4 d[4];
    #pragma unroll
    for (int mi = 0; mi < 4; ++mi) d[mi] = MFMA16(af, bfr[mi], z4);
    #pragma unroll
    for (int r = 0; r < 4; ++r) {
      float tm = fmaxf(fmaxf(d[0][r], d[1][r]), fmaxf(d[2][r], d[3][r]));
      float nm = fmaxf(rm[r], tm);
      zz[r] = zz[r] * exp2f(rm[r] - nm)
            + exp2f(d[0][r] - nm) + exp2f(d[1][r] - nm)
            + exp2f(d[2][r] - nm) + exp2f(d[3][r] - nm);
      rm[r] = nm;
    }
  }
  #pragma unroll
  for (int off = 1; off < 16; off <<= 1) {
    #pragma unroll
    for (int r = 0; r < 4; ++r) {
      float om = __shfl_xor(rm[r], off);
      float oz = __shfl_xor(zz[r], off);
      float nm = fmaxf(rm[r], om);
      zz[r] = zz[r] * exp2f(rm[r] - nm) + oz * exp2f(om - nm);
      rm[r] = nm;
    }
  }
  if (lm == 0) {
    #pragma unroll
    for (int r = 0; r < 4; ++r) {
      int n = n0 + 4 * g + r;
      size_t idx = ((size_t)ms * 16384 + (size_t)b * MM + n) * 2;
      LSEP[idx] = rm[r]; LSEP[idx + 1] = zz[r];
    }
  }
}

// ---------------- merge LSE partials ----------------
__global__ __launch_bounds__(256) void k_lsered(const float* __restrict__ LSEP,
                                                float* __restrict__ LSE) {
  int bn = blockIdx.x * 256 + threadIdx.x;  // < 16384
  float rm = -__builtin_inff(), zz = 0.f;
  #pragma unroll
  for (int ms = 0; ms < 4; ++ms) {
    float m = LSEP[((size_t)ms * 16384 + bn) * 2];
    float z = LSEP[((size_t)ms * 16384 + bn) * 2 + 1];
    float nm = fmaxf(rm, m);
    zz = zz * exp2f(rm - nm) + z * exp2f(m - nm);
    rm = nm;
  }
  LSE[bn] = rm + log2f(zz);
}

// ---------------- K-O: MFMA O-pass, triple-buffered LDS H (2-chunk-ahead prefetch) ----------------
// Hs layout per buffer: short offset = (ch>>4)*512 + sg*128 + (ch&15)*8
// wave read for subtile ct is contiguous 1KB at ct*512 + lane*8.
__global__ __launch_bounds__(256) void k_omfma(const unsigned short* __restrict__ FGT,
                                               const unsigned short* __restrict__ HB,
                                               const float* __restrict__ LSE,
                                               unsigned short* __restrict__ Opart) {
  __shared__ __align__(16) unsigned short Hs[3][9 * 512];  // 3 x 9KB
  int t = threadIdx.x; int w = t >> 6; int l = t & 63;
  int b = blockIdx.y; int split = blockIdx.z;
  int lm = l & 15, g = l >> 4;
  int mcol0 = blockIdx.x * 128 + w * 32 + lm;
  int mcol1 = mcol0 + 16;
  f32x4 z4 = {0.f, 0.f, 0.f, 0.f};
  short8 Ff0 = *(const short8*)&FGT[((size_t)b * MM + mcol0) * 64 + 8 * g];
  short8 Ff1 = *(const short8*)&FGT[((size_t)b * MM + mcol1) * 64 + 8 * g];
  f32x4 acc0[9], acc1[9];
  #pragma unroll
  for (int ct = 0; ct < 9; ++ct) { acc0[ct] = z4; acc1[ct] = z4; }
  const int nchunks = (split < 2) ? 22 : 21;
  const int startc = split * 21 + ((split < 2) ? split : 2);
  const int start = startc * 32;
  const unsigned short* gptr = FGT + ((size_t)b * MM + lm) * 64 + 32 + 8 * g;
  const unsigned short* hsrc = HB + (size_t)b * 144 * MM;
  const float* lbase = LSE + (size_t)b * MM + 4 * g;
  int src01 = lm + 16 * (2 * (g & 1));
  int src23 = src01 + 16;
  bool hi = g >= 2;
  // staging: 576 uint4 items; item (ch, sg) -> LDS short offset (ch>>4)*512 + sg*128 + (ch&15)*8
  int sidx0 = t, sidx1 = t + 256, sidx2 = t + 512;
  int ch0 = sidx0 >> 2, sg0 = sidx0 & 3;
  int ch1 = sidx1 >> 2, sg1 = sidx1 & 3;
  int ch2 = (sidx2 < 576) ? (sidx2 >> 2) : 0;
  int sg2 = sidx2 & 3;
  bool has2 = sidx2 < 576;
  int d0 = (ch0 >> 4) * 512 + sg0 * 128 + (ch0 & 15) * 8;
  int d1 = (ch1 >> 4) * 512 + sg1 * 128 + (ch1 & 15) * 8;
  int d2 = (ch2 >> 4) * 512 + sg2 * 128 + (ch2 & 15) * 8;

  // preamble: chunk 0 -> buf 0 (load+write); issue chunk 1 into reg set B
  {
    uint4 r0 = *(const uint4*)(hsrc + (size_t)ch0 * MM + start + sg0 * 8);
    uint4 r1 = *(const uint4*)(hsrc + (size_t)ch1 * MM + start + sg1 * 8);
    uint4 r2 = has2 ? *(const uint4*)(hsrc + (size_t)ch2 * MM + start + sg2 * 8) : uint4{0,0,0,0};
    *(uint4*)&Hs[0][d0] = r0;
    *(uint4*)&Hs[0][d1] = r1;
    if (has2) *(uint4*)&Hs[0][d2] = r2;
  }
  uint4 B0, B1, B2;
  if (nchunks > 1) {
    int n1 = start + 32;
    B0 = *(const uint4*)(hsrc + (size_t)ch0 * MM + n1 + sg0 * 8);
    B1 = *(const uint4*)(hsrc + (size_t)ch1 * MM + n1 + sg1 * 8);
    if (has2) B2 = *(const uint4*)(hsrc + (size_t)ch2 * MM + n1 + sg2 * 8);
  }
  // G/LSE for chunk 0
  short8 a0 = *(const short8*)(gptr + (size_t)start * 64);
  short8 a1 = *(const short8*)(gptr + (size_t)(start + 16) * 64);
  float4 l0 = *(const float4*)(lbase + start);
  float4 l1 = *(const float4*)(lbase + start + 16);
  __syncthreads();

  int cur = 0;
  for (int it = 0; it < nchunks; ++it) {
    int n0 = start + it * 32;
    bool more1 = (it + 1 < nchunks);
    bool more2 = (it + 2 < nchunks);
    int n1 = more1 ? (n0 + 32) : start;
    // (A) issue loads for chunk it+2 into reg set A (2-chunk latency window)
    uint4 A0, A1, A2;
    if (more2) {
      int n2 = n0 + 64;
      A0 = *(const uint4*)(hsrc + (size_t)ch0 * MM + n2 + sg0 * 8);
      A1 = *(const uint4*)(hsrc + (size_t)ch1 * MM + n2 + sg1 * 8);
      if (has2) A2 = *(const uint4*)(hsrc + (size_t)ch2 * MM + n2 + sg2 * 8);
    }
    // (B) write reg set B (chunk it+1, issued one full iter ago) into buf (cur+1)%3
    int wr = (cur == 2) ? 0 : cur + 1;
    if (more1) {
      *(uint4*)&Hs[wr][d0] = B0;
      *(uint4*)&Hs[wr][d1] = B1;
      if (has2) *(uint4*)&Hs[wr][d2] = B2;
    }
    // next G/LSE into regs
    short8 na0 = *(const short8*)(gptr + (size_t)n1 * 64);
    short8 na1 = *(const short8*)(gptr + (size_t)(n1 + 16) * 64);
    float4 nl0 = *(const float4*)(lbase + n1);
    float4 nl1 = *(const float4*)(lbase + n1 + 16);
    // (C) compute current chunk from LDS buf[cur] (contiguous 1KB per ct)
    short8 hf[9];
    #pragma unroll
    for (int ct = 0; ct < 9; ++ct)
      hf[ct] = *(const short8*)&Hs[cur][ct * 512 + l * 8];
    f32x4 s00 = MFMA16(a0, Ff0, z4);
    f32x4 s10 = MFMA16(a1, Ff0, z4);
    f32x4 s01 = MFMA16(a0, Ff1, z4);
    f32x4 s11 = MFMA16(a1, Ff1, z4);
    float le0[4] = {l0.x, l0.y, l0.z, l0.w};
    float le1[4] = {l1.x, l1.y, l1.z, l1.w};
    unsigned pk00[2], pk10[2], pk01[2], pk11[2];
    #pragma unroll
    for (int h2 = 0; h2 < 2; ++h2) {
      pk00[h2] = cvtpk(exp2f(s00[2*h2] - le0[2*h2]), exp2f(s00[2*h2+1] - le0[2*h2+1]));
      pk10[h2] = cvtpk(exp2f(s10[2*h2] - le1[2*h2]), exp2f(s10[2*h2+1] - le1[2*h2+1]));
      pk01[h2] = cvtpk(exp2f(s01[2*h2] - le0[2*h2]), exp2f(s01[2*h2+1] - le0[2*h2+1]));
      pk11[h2] = cvtpk(exp2f(s11[2*h2] - le1[2*h2]), exp2f(s11[2*h2+1] - le1[2*h2+1]));
    }
    unsigned a0w = (unsigned)__shfl((int)pk00[0], src01);
    unsigned b0w = (unsigned)__shfl((int)pk10[0], src01);
    unsigned a1w = (unsigned)__shfl((int)pk00[1], src01);
    unsigned b1w = (unsigned)__shfl((int)pk10[1], src01);
    unsigned a2w = (unsigned)__shfl((int)pk00[0], src23);
    unsigned b2w = (unsigned)__shfl((int)pk10[0], src23);
    unsigned a3w = (unsigned)__shfl((int)pk00[1], src23);
    unsigned b3w = (unsigned)__shfl((int)pk10[1], src23);
    union { unsigned u[4]; short8 s; } bu0;
    bu0.u[0] = hi ? b0w : a0w; bu0.u[1] = hi ? b1w : a1w;
    bu0.u[2] = hi ? b2w : a2w; bu0.u[3] = hi ? b3w : a3w;
    short8 bfrag0 = bu0.s;
    unsigned c0w = (unsigned)__shfl((int)pk01[0], src01);
    unsigned d0w = (unsigned)__shfl((int)pk11[0], src01);
    unsigned c1w = (unsigned)__shfl((int)pk01[1], src01);
    unsigned d1w = (unsigned)__shfl((int)pk11[1], src01);
    unsigned c2w = (unsigned)__shfl((int)pk01[0], src23);
    unsigned d2w = (unsigned)__shfl((int)pk11[0], src23);
    unsigned c3w = (unsigned)__shfl((int)pk01[1], src23);
    unsigned d3w = (unsigned)__shfl((int)pk11[1], src23);
    union { unsigned u[4]; short8 s; } bu1;
    bu1.u[0] = hi ? d0w : c0w; bu1.u[1] = hi ? d1w : c1w;
    bu1.u[2] = hi ? d2w : c2w; bu1.u[3] = hi ? d3w : c3w;
    short8 bfrag1 = bu1.s;
    __builtin_amdgcn_s_setprio(1);
    #pragma unroll
    for (int ct = 0; ct < 9; ++ct) {
      acc0[ct] = MFMA16(hf[ct], bfrag0, acc0[ct]);
      acc1[ct] = MFMA16(hf[ct], bfrag1, acc1[ct]);
    }
    __builtin_amdgcn_s_setprio(0);
    a0 = na0; a1 = na1; l0 = nl0; l1 = nl1;
    __syncthreads();
    // rotate: reg set A (chunk it+2) becomes set B for next iter
    B0 = A0; B1 = A1; B2 = A2;
    cur = wr;
  }

  unsigned short* op0 = Opart + (size_t)split * OPS_SH + ((size_t)b * MM + mcol0) * 132;
  unsigned short* op1 = Opart + (size_t)split * OPS_SH + ((size_t)b * MM + mcol1) * 132;
  #pragma unroll
  for (int ct = 0; ct < 9; ++ct) {
    int c0 = ct * 16 + 4 * g;
    if (c0 < 132) {
      uint2 p0, p1;
      p0.x = cvtpk(acc0[ct][0], acc0[ct][1]);
      p0.y = cvtpk(acc0[ct][2], acc0[ct][3]);
      p1.x = cvtpk(acc1[ct][0], acc1[ct][1]);
      p1.y = cvtpk(acc1[ct][2], acc1[ct][3]);
      *(uint2*)&op0[c0] = p0;
      *(uint2*)&op1[c0] = p1;
    }
  }
}

// ---------------- O reduce: A16 = bf16(gamma*sum(Oparts) + X) ----------------
__global__ __launch_bounds__(256) void k_ored(const unsigned short* __restrict__ Op,
                                              const unsigned short* __restrict__ X16,
                                              const float* __restrict__ gma,
                                              unsigned short* __restrict__ A16) {
  int i = blockIdx.x * 256 + threadIdx.x;  // < 327680
  int row = i / 20, c8 = i % 20;
  int c0 = c8 * 8;
  unsigned short* ap = A16 + (size_t)row * 160 + c0;
  if (c0 >= 136) {
    uint4 z = {0, 0, 0, 0};
    *(uint4*)ap = z;
    return;
  }
  float gm = gma[0];
  float ov[8] = {0.f, 0.f, 0.f, 0.f, 0.f, 0.f, 0.f, 0.f};
  #pragma unroll
  for (int s = 0; s < 6; ++s) {
    const unsigned short* base = Op + (size_t)s * OPS_SH + (size_t)row * 132 + c0;
    uint2 u = *(const uint2*)base;
    ov[0] += bf2f((unsigned short)(u.x & 0xffff));
    ov[1] += bf2f((unsigned short)(u.x >> 16));
    ov[2] += bf2f((unsigned short)(u.y & 0xffff));
    ov[3] += bf2f((unsigned short)(u.y >> 16));
    if (c0 + 4 < 132) {
      uint2 v = *(const uint2*)(base + 4);
      ov[4] += bf2f((unsigned short)(v.x & 0xffff));
      ov[5] += bf2f((unsigned short)(v.x >> 16));
      ov[6] += bf2f((unsigned short)(v.y & 0xffff));
      ov[7] += bf2f((unsigned short)(v.y >> 16));
    }
  }
  short8 xv = *(const short8*)(X16 + (size_t)row * 160 + c0);
  unsigned pw[4];
  #pragma unroll
  for (int h = 0; h < 4; ++h) {
    int ca = c0 + 2 * h, cb = c0 + 2 * h + 1;
    float xa = bf2f((unsigned short)xv[2 * h]);
    float xb = bf2f((unsigned short)xv[2 * h + 1]);
    float va = (ca < 132) ? (gm * ov[2 * h] + xa) : 0.f;
    float vb = (cb < 132) ? (gm * ov[2 * h + 1] + xb) : 0.f;
    pw[h] = (unsigned)f2bf(va) | ((unsigned)f2bf(vb) << 16);
  }
  uint4 pk = {pw[0], pw[1], pw[2], pw[3]};
  *(uint4*)ap = pk;
}

extern "C" void kernel_launch(void* const* d_in, const int* in_sizes, int n_in,
                              void* d_out, int out_size, void* d_ws, size_t ws_size,
                              hipStream_t stream) {
  const float* inp = (const float*)d_in[0];
  const float* Wa  = (const float*)d_in[1];
  const float* gna = (const float*)d_in[2];
  const float* bta = (const float*)d_in[3];
  const float* Wb  = (const float*)d_in[4];
  const float* gnb = (const float*)d_in[5];
  const float* btb = (const float*)d_in[6];
  const float* Wf  = (const float*)d_in[7];
  const float* bf  = (const float*)d_in[8];
  const float* gf  = (const float*)d_in[9];
  const float* bef = (const float*)d_in[10];
  const float* Wg  = (const float*)d_in[11];
  const float* bg  = (const float*)d_in[12];
  const float* gg  = (const float*)d_in[13];
  const float* beg = (const float*)d_in[14];
  const float* Wh  = (const float*)d_in[15];
  const float* bh  = (const float*)d_in[16];
  const float* gh  = (const float*)d_in[17];
  const float* beh = (const float*)d_in[18];
  const float* gamma = (const float*)d_in[19];
  const float* W1  = (const float*)d_in[20];
  const float* b1  = (const float*)d_in[21];
  const float* W2  = (const float*)d_in[22];
  const float* b2  = (const float*)d_in[23];
  float* out = (float*)d_out;

  float* ws = (float*)d_ws;
  float* DIST = ws + OFF_DIST;
  float* PM   = ws + OFF_PM;
  float* QM   = ws + OFF_QM;
  float* HRAW = ws + OFF_HRAW;
  float* FGRAW= ws + OFF_FGRAW;
  unsigned short* OP16 = (unsigned short*)(ws + OFF_OP);
  unsigned short* FGT = (unsigned short*)(ws + OFF_FGT);
  unsigned short* HBB = (unsigned short*)(ws + OFF_HB);
  unsigned short* A16 = (unsigned short*)(ws + OFF_A16);
  unsigned short* X16 = (unsigned short*)(ws + OFF_X16);
  unsigned short* Y1  = (unsigned short*)(ws + OFF_Y1);
  float* LSEB = ws + OFF_LSE;
  float* LSEP = ws + OFF_LSEP;
  float* STATS= ws + OFF_STATS;
  float* ABE  = ws + OFF_ABE;
  float* ABH  = ws + OFF_ABH;
  float* FGP  = ws + OFF_FGP;
  float* BIAS = ws + OFF_BIAS;
  unsigned short* W16 = (unsigned short*)(ws + OFF_W16);
  int*   KNNI = (int*)(ws + OFF_KNN);
  float* XN   = ws + OFF_XN;
  unsigned short* XR = (unsigned short*)(ws + OFF_XR);
  unsigned short* WPQ = (unsigned short*)(ws + OFF_WPQ);
  float* SQ   = ws + OFF_SQ;

  // 0. fused prep + normalize
  k_init<<<949, 256, 0, stream>>>(Wf, Wg, Wh, W1, W2, bf, bg, bh, b1, b2, Wa, Wb, W16, BIAS, WPQ,
                                  inp, XN, XR, SQ);
  // 1-2. fp32 dist 128x64 (exact kNN path), knn
  k_dist<<<dim3(16, 8, 4), 256, 0, stream>>>(XN, SQ, DIST);
  k_knn<<<4096, 64, 0, stream>>>(DIST, KNNI);
  // 3. P/Q MFMA (overwrites DIST) ; 4-5. edge BN ; 6. apply -> X16
  k_pqm<<<dim3(16, 4, 8), 256, 0, stream>>>(XR, WPQ, PM, QM);
  k_edge_stats<<<dim3(16, 4, 2), 256, 0, stream>>>(PM, QM, KNNI, STATS);
  k_edge_fin<<<2, 256, 0, stream>>>(STATS, gna, bta, gnb, btb, ABE);
  k_edge_apply<<<dim3(1024, 4), 256, 0, stream>>>(PM, QM, KNNI, ABE, X16);
  // 7. f+g conv (f32 m-major raw) and h conv (f32 ch-major raw), over dead PM/QM region
  k_convm<5, 2, 0, false><<<dim3(64, 2, 4), 256, 0, stream>>>(X16, W16 + W16_FG, BIAS + B_FG, FGRAW, nullptr, 64, 0);
  k_convm<5, 3, 2, false><<<dim3(64, 3, 4), 256, 0, stream>>>(X16, W16 + W16_H, BIAS + B_H, HRAW, nullptr, 0, 144);
  // 8. merged BN stats + merged cvt
  k_stats<<<194, 256, 0, stream>>>(FGRAW, FGP, HRAW, gh, beh, ABH);
  k_cvt<<<2816, 256, 0, stream>>>(FGRAW, FGP, gf, bef, gg, beg, FGT, HRAW, ABH, HBB);
  // 9. LSE ; 10. O-pass (triple-buffered H prefetch) ; 11. reduce -> A16
  k_zlse<<<dim3(64, 4, 4), 256, 0, stream>>>(FGT, LSEP);
  k_lsered<<<64, 256, 0, stream>>>(LSEP, LSEB);
  k_omfma<<<dim3(32, 4, 6), 256, 0, stream>>>(FGT, HBB, LSEB, OP16);
  k_ored<<<1280, 256, 0, stream>>>(OP16, X16, gamma, A16);
  // 12-13. final convs (MFMA)
  k_convm<5, 8, 1, true><<<dim3(64, 2, 4), 256, 0, stream>>>(A16, W16 + W16_C1, BIAS + B_C1, nullptr, Y1, 256, 0);
  k_convm<8, 4, 2, true><<<dim3(64, 2, 4), 256, 0, stream>>>(Y1, W16 + W16_C2, BIAS + B_C2, out, nullptr, 0, 128);
}